// Round 1
// baseline (1714.856 us; speedup 1.0000x reference)
//
#include <hip/hip_runtime.h>

namespace {
constexpr int N_ = 16, C_ = 32, V_ = 512, T_ = 64;
constexpr int H_ = 4, D_ = 16, OC_ = 64;
constexpr int EMB_ = 64;
constexpr int CV_ = C_ * V_;          // 16384
constexpr int VT_ = V_ * T_;          // 32768
constexpr int CVT_ = C_ * V_ * T_;    // 1048576
constexpr int GCIN_ = 7 * C_;         // 224
}

// ---------------------------------------------------------------------------
// Kernel 1: per-(n,h) attention rows. att[n,h,t,p] = softmax_p(q_t . k_p / 4)
// block = 64 threads (1 wave), thread t owns row t.
// ---------------------------------------------------------------------------
__global__ __launch_bounds__(64) void att_kernel(
    const float* __restrict__ t_in, const float* __restrict__ factors,
    const float* __restrict__ Wq, const float* __restrict__ Wk,
    float* __restrict__ att)
{
    const int n = blockIdx.x >> 2;
    const int h = blockIdx.x & 3;
    const int t = threadIdx.x;   // 0..63

    __shared__ float wq_l[EMB_][D_];
    __shared__ float wk_l[EMB_][D_];
    __shared__ float k_l[T_][D_ + 1];

#pragma unroll
    for (int d = 0; d < D_; ++d) {
        wq_l[t][d] = Wq[(h * EMB_ + t) * D_ + d];
        wk_l[t][d] = Wk[(h * EMB_ + t) * D_ + d];
    }
    __syncthreads();

    const float tv = t_in[n * T_ + t];
    const float fh = factors[h];
    float emb[EMB_];
#pragma unroll
    for (int j = 0; j < 32; ++j) {
        float dt = __expf((float)(2 * j) * fh);
        float ph = tv * dt;
        float s, c;
        __sincosf(ph, &s, &c);
        emb[j] = s;
        emb[j + 32] = c;
    }

    float q[D_];
#pragma unroll
    for (int d = 0; d < D_; ++d) {
        float aq = 0.f, ak = 0.f;
#pragma unroll
        for (int f = 0; f < EMB_; ++f) {
            aq += emb[f] * wq_l[f][d];
            ak += emb[f] * wk_l[f][d];
        }
        q[d] = aq;
        k_l[t][d] = ak;
    }
    __syncthreads();

    float L[T_];
    float m = -1e30f;
#pragma unroll
    for (int j = 0; j < T_; ++j) {
        float a = 0.f;
#pragma unroll
        for (int d = 0; d < D_; ++d) a += q[d] * k_l[j][d];
        a *= 0.25f;   // 1/sqrt(D=16)
        L[j] = a;
        m = fmaxf(m, a);
    }
    float ssum = 0.f;
#pragma unroll
    for (int j = 0; j < T_; ++j) {
        float e = __expf(L[j] - m);
        L[j] = e;
        ssum += e;
    }
    const float inv = 1.f / ssum;
    float* arow = att + (((size_t)(n * H_ + h) * T_ + t) * T_);
#pragma unroll
    for (int j = 0; j < T_; ++j) arow[j] = L[j] * inv;
}

// ---------------------------------------------------------------------------
// Kernel 2: S[n,i,j] = sum_h att[n,h,i,j]
// ---------------------------------------------------------------------------
__global__ __launch_bounds__(256) void sred_kernel(
    const float* __restrict__ att, float* __restrict__ S)
{
    int g = blockIdx.x * 256 + threadIdx.x;
    if (g >= N_ * T_ * T_) return;
    int n = g / (T_ * T_);
    int ij = g - n * (T_ * T_);
    float a = 0.f;
#pragma unroll
    for (int h = 0; h < H_; ++h) a += att[(size_t)(n * H_ + h) * (T_ * T_) + ij];
    S[g] = a;
}

// ---------------------------------------------------------------------------
// Kernel 3: xt[row, i] = sum_j x[row, j] * S[n, i, j]   (row = c*V+v within n)
// block 256 threads handles 64 rows of one n.
// ---------------------------------------------------------------------------
__global__ __launch_bounds__(256) void xt_kernel(
    const float* __restrict__ x, const float* __restrict__ S,
    float* __restrict__ xt, int n0)
{
    const int nl = blockIdx.y;
    const int ng = n0 + nl;
    const int r0 = blockIdx.x * 64;
    const int tid = threadIdx.x;

    __shared__ float sS[T_][68];
    __shared__ float sX[64][68];

#pragma unroll
    for (int k = 0; k < 4; ++k) {
        int lin = k * 256 + tid;           // 0..1023
        int r = lin >> 4, cq = lin & 15;
        *(float4*)&sS[r][cq * 4] = *(const float4*)&S[((size_t)ng * T_ + r) * T_ + cq * 4];
        *(float4*)&sX[r][cq * 4] = *(const float4*)&x[((size_t)ng * CV_ + r0 + r) * T_ + cq * 4];
    }
    __syncthreads();

    const int rl = tid >> 2;
    const int ig = tid & 3;
    float4 xr[16];
#pragma unroll
    for (int jq = 0; jq < 16; ++jq) xr[jq] = *(float4*)&sX[rl][jq * 4];

    float acc[16];
#pragma unroll
    for (int i = 0; i < 16; ++i) {
        int irow = ig * 16 + i;
        float a = 0.f;
#pragma unroll
        for (int jq = 0; jq < 16; ++jq) {
            float4 s4 = *(float4*)&sS[irow][jq * 4];
            float4 x4 = xr[jq];
            a += s4.x * x4.x + s4.y * x4.y + s4.z * x4.z + s4.w * x4.w;
        }
        acc[i] = a;
    }
    float* orow = xt + ((size_t)nl * CV_ + r0 + rl) * T_ + ig * 16;
#pragma unroll
    for (int q4 = 0; q4 < 4; ++q4)
        *(float4*)&orow[q4 * 4] =
            make_float4(acc[q4 * 4], acc[q4 * 4 + 1], acc[q4 * 4 + 2], acc[q4 * 4 + 3]);
}

// ---------------------------------------------------------------------------
// Kernel 4: diffusion GEMM  out[b,w,l] = sum_v A[v,w] * in[b,v,l]
// block 256, tile 128(w) x 64(l), micro-tile 8x4 per thread.
// ---------------------------------------------------------------------------
__global__ __launch_bounds__(256) void diff_kernel(
    const float* __restrict__ A, const float* __restrict__ in,
    float* __restrict__ out)
{
    const int b = blockIdx.y;
    const int w0 = blockIdx.x * 128;
    const int tid = threadIdx.x;

    __shared__ float sA[16][132];
    __shared__ float sX[16][68];

    float acc[8][4];
#pragma unroll
    for (int i = 0; i < 8; ++i)
#pragma unroll
        for (int j = 0; j < 4; ++j) acc[i][j] = 0.f;

    const float* inb = in + (size_t)b * VT_;
    const int tw0 = (tid >> 4) * 8;
    const int tl0 = (tid & 15) * 4;

    for (int v0 = 0; v0 < V_; v0 += 16) {
#pragma unroll
        for (int k = 0; k < 2; ++k) {
            int lin = k * 256 + tid;       // 0..511
            int vv = lin >> 5, wq = lin & 31;
            *(float4*)&sA[vv][wq * 4] = *(const float4*)&A[(size_t)(v0 + vv) * V_ + w0 + wq * 4];
        }
        {
            int vv = tid >> 4, lq = tid & 15;
            *(float4*)&sX[vv][lq * 4] = *(const float4*)&inb[(size_t)(v0 + vv) * T_ + lq * 4];
        }
        __syncthreads();
#pragma unroll
        for (int vv = 0; vv < 16; ++vv) {
            float4 a0 = *(float4*)&sA[vv][tw0];
            float4 a1 = *(float4*)&sA[vv][tw0 + 4];
            float4 x4 = *(float4*)&sX[vv][tl0];
            float av0 = a0.x, av1 = a0.y, av2 = a0.z, av3 = a0.w;
            float av4 = a1.x, av5 = a1.y, av6 = a1.z, av7 = a1.w;
            acc[0][0] += av0 * x4.x; acc[0][1] += av0 * x4.y; acc[0][2] += av0 * x4.z; acc[0][3] += av0 * x4.w;
            acc[1][0] += av1 * x4.x; acc[1][1] += av1 * x4.y; acc[1][2] += av1 * x4.z; acc[1][3] += av1 * x4.w;
            acc[2][0] += av2 * x4.x; acc[2][1] += av2 * x4.y; acc[2][2] += av2 * x4.z; acc[2][3] += av2 * x4.w;
            acc[3][0] += av3 * x4.x; acc[3][1] += av3 * x4.y; acc[3][2] += av3 * x4.z; acc[3][3] += av3 * x4.w;
            acc[4][0] += av4 * x4.x; acc[4][1] += av4 * x4.y; acc[4][2] += av4 * x4.z; acc[4][3] += av4 * x4.w;
            acc[5][0] += av5 * x4.x; acc[5][1] += av5 * x4.y; acc[5][2] += av5 * x4.z; acc[5][3] += av5 * x4.w;
            acc[6][0] += av6 * x4.x; acc[6][1] += av6 * x4.y; acc[6][2] += av6 * x4.z; acc[6][3] += av6 * x4.w;
            acc[7][0] += av7 * x4.x; acc[7][1] += av7 * x4.y; acc[7][2] += av7 * x4.z; acc[7][3] += av7 * x4.w;
        }
        __syncthreads();
    }

#pragma unroll
    for (int i = 0; i < 8; ++i) {
        *(float4*)&out[((size_t)b * V_ + w0 + tw0 + i) * T_ + tl0] =
            make_float4(acc[i][0], acc[i][1], acc[i][2], acc[i][3]);
    }
}

// ---------------------------------------------------------------------------
// Kernel 5: out init: out[ng,o,v,:] = b_out[o] + W0@xt + BN(W_res@x)
// block per (v, nl); thread: o = tid>>2, 16 t's.
// ---------------------------------------------------------------------------
__global__ __launch_bounds__(256) void initout_kernel(
    const float* __restrict__ x, const float* __restrict__ xt,
    const float* __restrict__ W_out, const float* __restrict__ b_out,
    const float* __restrict__ W_res, const float* __restrict__ b_res,
    const float* __restrict__ gamma, const float* __restrict__ beta,
    const float* __restrict__ mean, const float* __restrict__ var,
    float* __restrict__ out, int n0)
{
    const int v = blockIdx.x;
    const int nl = blockIdx.y;
    const int ng = n0 + nl;
    const int tid = threadIdx.x;

    __shared__ float sxt[C_][68];
    __shared__ float sx[C_][68];
    __shared__ float w0[OC_][C_];
    __shared__ float wr[OC_][C_];
    __shared__ float bias[OC_];

#pragma unroll
    for (int k = 0; k < 8; ++k) {
        int lin = k * 256 + tid;   // 0..2047
        int o = lin >> 5, c = lin & 31;
        w0[o][c] = W_out[o * GCIN_ + c];
        float rs = gamma[o] * rsqrtf(var[o] + 1e-5f);
        wr[o][c] = rs * W_res[o * C_ + c];
    }
    if (tid < OC_) {
        float rs = gamma[tid] * rsqrtf(var[tid] + 1e-5f);
        bias[tid] = b_out[tid] + beta[tid] + rs * (b_res[tid] - mean[tid]);
    }
#pragma unroll
    for (int k = 0; k < 2; ++k) {
        int lin = k * 256 + tid;   // 0..511
        int c = lin >> 4, tq = lin & 15;
        *(float4*)&sxt[c][tq * 4] = *(const float4*)&xt[(((size_t)nl * C_ + c) * V_ + v) * T_ + tq * 4];
        *(float4*)&sx[c][tq * 4]  = *(const float4*)&x[(((size_t)ng * C_ + c) * V_ + v) * T_ + tq * 4];
    }
    __syncthreads();

    const int o = tid >> 2;
    const int t0 = (tid & 3) * 16;
    float acc[16];
    const float bb = bias[o];
#pragma unroll
    for (int i = 0; i < 16; ++i) acc[i] = bb;
#pragma unroll
    for (int c = 0; c < C_; ++c) {
        float a = w0[o][c], bw = wr[o][c];
#pragma unroll
        for (int q = 0; q < 4; ++q) {
            float4 x4 = *(float4*)&sxt[c][t0 + q * 4];
            float4 y4 = *(float4*)&sx[c][t0 + q * 4];
            acc[q * 4 + 0] += a * x4.x + bw * y4.x;
            acc[q * 4 + 1] += a * x4.y + bw * y4.y;
            acc[q * 4 + 2] += a * x4.z + bw * y4.z;
            acc[q * 4 + 3] += a * x4.w + bw * y4.w;
        }
    }
    float* orow = out + (((size_t)ng * OC_ + o) * V_ + v) * T_ + t0;
#pragma unroll
    for (int q = 0; q < 4; ++q)
        *(float4*)&orow[q * 4] =
            make_float4(acc[q * 4], acc[q * 4 + 1], acc[q * 4 + 2], acc[q * 4 + 3]);
}

// ---------------------------------------------------------------------------
// Kernel 6: out += W1@x1 + W2@x2 ; optional PReLU at the end.
// ---------------------------------------------------------------------------
__global__ __launch_bounds__(256) void accum_kernel(
    const float* __restrict__ x1, const float* __restrict__ x2,
    const float* __restrict__ W_out, const float* __restrict__ alpha_p,
    float* __restrict__ out, int n0, int cbase, int do_prelu)
{
    const int v = blockIdx.x;
    const int nl = blockIdx.y;
    const int ng = n0 + nl;
    const int tid = threadIdx.x;

    __shared__ float s1[C_][68];
    __shared__ float s2[C_][68];
    __shared__ float w1[OC_][C_];
    __shared__ float w2[OC_][C_];

#pragma unroll
    for (int k = 0; k < 8; ++k) {
        int lin = k * 256 + tid;
        int o = lin >> 5, c = lin & 31;
        w1[o][c] = W_out[o * GCIN_ + cbase + c];
        w2[o][c] = W_out[o * GCIN_ + cbase + C_ + c];
    }
#pragma unroll
    for (int k = 0; k < 2; ++k) {
        int lin = k * 256 + tid;
        int c = lin >> 4, tq = lin & 15;
        *(float4*)&s1[c][tq * 4] = *(const float4*)&x1[(((size_t)nl * C_ + c) * V_ + v) * T_ + tq * 4];
        *(float4*)&s2[c][tq * 4] = *(const float4*)&x2[(((size_t)nl * C_ + c) * V_ + v) * T_ + tq * 4];
    }
    __syncthreads();

    const int o = tid >> 2;
    const int t0 = (tid & 3) * 16;
    float* orow = out + (((size_t)ng * OC_ + o) * V_ + v) * T_ + t0;

    float acc[16];
#pragma unroll
    for (int q = 0; q < 4; ++q) {
        float4 c4 = *(float4*)&orow[q * 4];
        acc[q * 4 + 0] = c4.x; acc[q * 4 + 1] = c4.y;
        acc[q * 4 + 2] = c4.z; acc[q * 4 + 3] = c4.w;
    }
#pragma unroll
    for (int c = 0; c < C_; ++c) {
        float a = w1[o][c], bw = w2[o][c];
#pragma unroll
        for (int q = 0; q < 4; ++q) {
            float4 x4 = *(float4*)&s1[c][t0 + q * 4];
            float4 y4 = *(float4*)&s2[c][t0 + q * 4];
            acc[q * 4 + 0] += a * x4.x + bw * y4.x;
            acc[q * 4 + 1] += a * x4.y + bw * y4.y;
            acc[q * 4 + 2] += a * x4.z + bw * y4.z;
            acc[q * 4 + 3] += a * x4.w + bw * y4.w;
        }
    }
    if (do_prelu) {
        float al = alpha_p[0];
#pragma unroll
        for (int i = 0; i < 16; ++i) acc[i] = acc[i] > 0.f ? acc[i] : al * acc[i];
    }
#pragma unroll
    for (int q = 0; q < 4; ++q)
        *(float4*)&orow[q * 4] =
            make_float4(acc[q * 4], acc[q * 4 + 1], acc[q * 4 + 2], acc[q * 4 + 3]);
}

// ---------------------------------------------------------------------------
extern "C" void kernel_launch(void* const* d_in, const int* in_sizes, int n_in,
                              void* d_out, int out_size, void* d_ws, size_t ws_size,
                              hipStream_t stream)
{
    const float* x       = (const float*)d_in[0];
    const float* t_in    = (const float*)d_in[1];
    const float* A[3]    = {(const float*)d_in[2], (const float*)d_in[3], (const float*)d_in[4]};
    const float* factors = (const float*)d_in[5];
    const float* Wq      = (const float*)d_in[6];
    const float* Wk      = (const float*)d_in[7];
    const float* W_out   = (const float*)d_in[8];
    const float* b_out   = (const float*)d_in[9];
    const float* W_res   = (const float*)d_in[10];
    const float* b_res   = (const float*)d_in[11];
    const float* gamma   = (const float*)d_in[12];
    const float* beta    = (const float*)d_in[13];
    const float* mean    = (const float*)d_in[14];
    const float* var     = (const float*)d_in[15];
    const float* alpha   = (const float*)d_in[16];
    float* out = (float*)d_out;

    float* att = (float*)d_ws;                       // N*H*T*T   = 262144 f
    float* S   = att + (size_t)N_ * H_ * T_ * T_;    // N*T*T     = 65536 f
    size_t fixed_bytes = ((size_t)N_ * H_ * T_ * T_ + (size_t)N_ * T_ * T_) * 4;

    int Nc = 16;
    while (Nc > 1 && fixed_bytes + (size_t)3 * Nc * CVT_ * 4 > ws_size) Nc >>= 1;

    float* xt = S + (size_t)N_ * T_ * T_;
    float* x1 = xt + (size_t)Nc * CVT_;
    float* x2 = x1 + (size_t)Nc * CVT_;

    att_kernel<<<N_ * H_, 64, 0, stream>>>(t_in, factors, Wq, Wk, att);
    sred_kernel<<<(N_ * T_ * T_ + 255) / 256, 256, 0, stream>>>(att, S);

    for (int n0 = 0; n0 < N_; n0 += Nc) {
        xt_kernel<<<dim3(CV_ / 64, Nc), 256, 0, stream>>>(x, S, xt, n0);
        initout_kernel<<<dim3(V_, Nc), 256, 0, stream>>>(
            x, xt, W_out, b_out, W_res, b_res, gamma, beta, mean, var, out, n0);
        for (int s = 0; s < 3; ++s) {
            diff_kernel<<<dim3(4, Nc * C_), 256, 0, stream>>>(A[s], xt, x1);
            diff_kernel<<<dim3(4, Nc * C_), 256, 0, stream>>>(A[s], x1, x2);
            accum_kernel<<<dim3(V_, Nc), 256, 0, stream>>>(
                x1, x2, W_out, alpha, out, n0, 32 * (1 + 2 * s), s == 2 ? 1 : 0);
        }
    }
}

// Round 2
// 1158.183 us; speedup vs baseline: 1.4806x; 1.4806x over previous
//
#include <hip/hip_runtime.h>

namespace {
constexpr int N_ = 16, C_ = 32, V_ = 512, T_ = 64;
constexpr int H_ = 4, D_ = 16, OC_ = 64;
constexpr int EMB_ = 64;
constexpr int GCIN_ = 7 * C_;         // 224
constexpr int TV_ = T_ * V_;          // 32768 (one slice, [t][v] f16 layout)
}

typedef _Float16 f16x8 __attribute__((ext_vector_type(8)));
typedef float f32x4 __attribute__((ext_vector_type(4)));

// ---------------------------------------------------------------------------
// Kernel 1: per-(n,h) attention rows. att[n,h,t,p] = softmax_p(q_t . k_p / 4)
// ---------------------------------------------------------------------------
__global__ __launch_bounds__(64) void att_kernel(
    const float* __restrict__ t_in, const float* __restrict__ factors,
    const float* __restrict__ Wq, const float* __restrict__ Wk,
    float* __restrict__ att)
{
    const int n = blockIdx.x >> 2;
    const int h = blockIdx.x & 3;
    const int t = threadIdx.x;   // 0..63

    __shared__ float wq_l[EMB_][D_];
    __shared__ float wk_l[EMB_][D_];
    __shared__ float k_l[T_][D_ + 1];

#pragma unroll
    for (int d = 0; d < D_; ++d) {
        wq_l[t][d] = Wq[(h * EMB_ + t) * D_ + d];
        wk_l[t][d] = Wk[(h * EMB_ + t) * D_ + d];
    }
    __syncthreads();

    const float tv = t_in[n * T_ + t];
    const float fh = factors[h];
    float emb[EMB_];
#pragma unroll
    for (int j = 0; j < 32; ++j) {
        float dt = __expf((float)(2 * j) * fh);
        float ph = tv * dt;
        float s, c;
        __sincosf(ph, &s, &c);
        emb[j] = s;
        emb[j + 32] = c;
    }

    float q[D_];
#pragma unroll
    for (int d = 0; d < D_; ++d) {
        float aq = 0.f, ak = 0.f;
#pragma unroll
        for (int f = 0; f < EMB_; ++f) {
            aq += emb[f] * wq_l[f][d];
            ak += emb[f] * wk_l[f][d];
        }
        q[d] = aq;
        k_l[t][d] = ak;
    }
    __syncthreads();

    float L[T_];
    float m = -1e30f;
#pragma unroll
    for (int j = 0; j < T_; ++j) {
        float a = 0.f;
#pragma unroll
        for (int d = 0; d < D_; ++d) a += q[d] * k_l[j][d];
        a *= 0.25f;
        L[j] = a;
        m = fmaxf(m, a);
    }
    float ssum = 0.f;
#pragma unroll
    for (int j = 0; j < T_; ++j) {
        float e = __expf(L[j] - m);
        L[j] = e;
        ssum += e;
    }
    const float inv = 1.f / ssum;
    float* arow = att + (((size_t)(n * H_ + h) * T_ + t) * T_);
#pragma unroll
    for (int j = 0; j < T_; ++j) arow[j] = L[j] * inv;
}

// ---------------------------------------------------------------------------
// Kernel 2: S[n,i,j] = sum_h att[n,h,i,j]
// ---------------------------------------------------------------------------
__global__ __launch_bounds__(256) void sred_kernel(
    const float* __restrict__ att, float* __restrict__ S)
{
    int g = blockIdx.x * 256 + threadIdx.x;
    if (g >= N_ * T_ * T_) return;
    int n = g / (T_ * T_);
    int ij = g - n * (T_ * T_);
    float a = 0.f;
#pragma unroll
    for (int h = 0; h < H_; ++h) a += att[(size_t)(n * H_ + h) * (T_ * T_) + ij];
    S[g] = a;
}

// ---------------------------------------------------------------------------
// Kernel 3: At16[s][w][v] = (f16) A_s[v][w]   (transpose + cast)
// ---------------------------------------------------------------------------
__global__ __launch_bounds__(256) void prepAt_kernel(
    const float* __restrict__ A0, const float* __restrict__ A1,
    const float* __restrict__ A2, _Float16* __restrict__ At16)
{
    const int s = blockIdx.z;
    const float* A = (s == 0) ? A0 : ((s == 1) ? A1 : A2);
    const int v0 = blockIdx.y * 32, w0 = blockIdx.x * 32;
    const int tid = threadIdx.x;
    __shared__ float sT[32][33];
#pragma unroll
    for (int k = 0; k < 4; ++k) {
        int lin = k * 256 + tid;
        int i = lin >> 5, w = lin & 31;
        sT[i][w] = A[(size_t)(v0 + i) * V_ + w0 + w];
    }
    __syncthreads();
#pragma unroll
    for (int k = 0; k < 4; ++k) {
        int lin = k * 256 + tid;
        int j = lin >> 5, i = lin & 31;
        At16[(size_t)s * V_ * V_ + (size_t)(w0 + j) * V_ + v0 + i] = (_Float16)sT[i][j];
    }
}

// ---------------------------------------------------------------------------
// Kernel 4: xtT[b][p][v] = sum_j S[n][p][j] * x[b][v][j]   (f16 out, MFMA)
// A-operand: S (M=p, K=j), B-operand: x slice (N=v, K=j). Both K-contig.
// ---------------------------------------------------------------------------
__global__ __launch_bounds__(256) void xtT_kernel(
    const float* __restrict__ x, const float* __restrict__ S,
    _Float16* __restrict__ XT, int n0)
{
    const int b = blockIdx.y;                 // local slice 0..Nc*C-1
    const int n = n0 + b / C_;
    const int lane = threadIdx.x & 63;
    const int wav = threadIdx.x >> 6;
    const int vbase = blockIdx.x * 256 + wav * 64;
    const int row16 = lane & 15;
    const int kg = lane >> 4;

    const float* Sn = S + (size_t)n * (T_ * T_);
    const float* xb = x + ((size_t)(n0 * C_) + b) * (V_ * T_);

    f32x4 acc[4][4];
#pragma unroll
    for (int i = 0; i < 4; ++i)
#pragma unroll
        for (int j = 0; j < 4; ++j) acc[i][j] = (f32x4){0.f, 0.f, 0.f, 0.f};

#pragma unroll
    for (int ks = 0; ks < 2; ++ks) {
        f16x8 a[4], bf[4];
#pragma unroll
        for (int mt = 0; mt < 4; ++mt) {
            const float* p = Sn + (size_t)(mt * 16 + row16) * T_ + ks * 32 + kg * 8;
            float4 u = *(const float4*)p;
            float4 w = *(const float4*)(p + 4);
            f16x8 t8;
            t8[0] = (_Float16)u.x; t8[1] = (_Float16)u.y; t8[2] = (_Float16)u.z; t8[3] = (_Float16)u.w;
            t8[4] = (_Float16)w.x; t8[5] = (_Float16)w.y; t8[6] = (_Float16)w.z; t8[7] = (_Float16)w.w;
            a[mt] = t8;
        }
#pragma unroll
        for (int nt = 0; nt < 4; ++nt) {
            const float* p = xb + (size_t)(vbase + nt * 16 + row16) * T_ + ks * 32 + kg * 8;
            float4 u = *(const float4*)p;
            float4 w = *(const float4*)(p + 4);
            f16x8 t8;
            t8[0] = (_Float16)u.x; t8[1] = (_Float16)u.y; t8[2] = (_Float16)u.z; t8[3] = (_Float16)u.w;
            t8[4] = (_Float16)w.x; t8[5] = (_Float16)w.y; t8[6] = (_Float16)w.z; t8[7] = (_Float16)w.w;
            bf[nt] = t8;
        }
#pragma unroll
        for (int nt = 0; nt < 4; ++nt)
#pragma unroll
            for (int mt = 0; mt < 4; ++mt)
                acc[mt][nt] = __builtin_amdgcn_mfma_f32_16x16x32_f16(a[mt], bf[nt], acc[mt][nt], 0, 0, 0);
    }

    _Float16* Yb = XT + (size_t)b * TV_;
#pragma unroll
    for (int mt = 0; mt < 4; ++mt)
#pragma unroll
        for (int nt = 0; nt < 4; ++nt)
#pragma unroll
            for (int r = 0; r < 4; ++r) {
                int t = mt * 16 + kg * 4 + r;
                int v = vbase + nt * 16 + row16;
                Yb[(size_t)t * V_ + v] = (_Float16)acc[mt][nt][r];
            }
}

// ---------------------------------------------------------------------------
// Kernel 5: diffusion hop  Y[b][t][w] = sum_v X[b][t][v] * At16[w][v]
// (= sum_v A[v,w] * X[t,v]). MFMA f16, operands direct from global (L2).
// ---------------------------------------------------------------------------
__global__ __launch_bounds__(256) void hop_kernel(
    const _Float16* __restrict__ At, const _Float16* __restrict__ X,
    _Float16* __restrict__ Y)
{
    const int b = blockIdx.y;
    const int lane = threadIdx.x & 63;
    const int wav = threadIdx.x >> 6;
    const int wbase = blockIdx.x * 256 + wav * 64;
    const int row16 = lane & 15;
    const int kg = lane >> 4;

    const _Float16* Xb = X + (size_t)b * TV_;
    const _Float16* ax = Xb + (size_t)row16 * V_ + kg * 8;
    const _Float16* bx = At + (size_t)(wbase + row16) * V_ + kg * 8;

    f32x4 acc[4][4];
#pragma unroll
    for (int i = 0; i < 4; ++i)
#pragma unroll
        for (int j = 0; j < 4; ++j) acc[i][j] = (f32x4){0.f, 0.f, 0.f, 0.f};

    for (int v0 = 0; v0 < V_; v0 += 32) {
        f16x8 a[4], bf[4];
#pragma unroll
        for (int mt = 0; mt < 4; ++mt)
            a[mt] = *(const f16x8*)(ax + (size_t)mt * 16 * V_ + v0);
#pragma unroll
        for (int nt = 0; nt < 4; ++nt)
            bf[nt] = *(const f16x8*)(bx + (size_t)nt * 16 * V_ + v0);
#pragma unroll
        for (int nt = 0; nt < 4; ++nt)
#pragma unroll
            for (int mt = 0; mt < 4; ++mt)
                acc[mt][nt] = __builtin_amdgcn_mfma_f32_16x16x32_f16(a[mt], bf[nt], acc[mt][nt], 0, 0, 0);
    }

    _Float16* Yb = Y + (size_t)b * TV_;
#pragma unroll
    for (int mt = 0; mt < 4; ++mt)
#pragma unroll
        for (int nt = 0; nt < 4; ++nt)
#pragma unroll
            for (int r = 0; r < 4; ++r) {
                int t = mt * 16 + kg * 4 + r;
                int w = wbase + nt * 16 + row16;
                Yb[(size_t)t * V_ + w] = (_Float16)acc[mt][nt][r];
            }
}

// ---------------------------------------------------------------------------
// Kernel 6: fused epilogue.
// out[ng,o,v,t] = PReLU( b_out[o] + sum_{c=0..223} W_out[o,c]*h[c][t][v]
//                        + BN( sum_c W_res[o,c]*x[ng,c,v,t] + b_res ) )
// Block: (v-tile 32, t-tile 8, nl). Thread: o = tid&63, vg = tid>>6 (8 v's).
// ---------------------------------------------------------------------------
#define EPI_COMPUTE()                                                          \
    _Pragma("unroll")                                                          \
    for (int c = 0; c < 8; ++c) {                                              \
        const float wv = sW[c][o];                                             \
        _Pragma("unroll")                                                      \
        for (int tt = 0; tt < 8; ++tt) {                                       \
            const float4 hA = *(const float4*)&sH[c][tt][vg * 8];              \
            const float4 hB = *(const float4*)&sH[c][tt][vg * 8 + 4];          \
            acc[0][tt] += wv * hA.x; acc[1][tt] += wv * hA.y;                  \
            acc[2][tt] += wv * hA.z; acc[3][tt] += wv * hA.w;                  \
            acc[4][tt] += wv * hB.x; acc[5][tt] += wv * hB.y;                  \
            acc[6][tt] += wv * hB.z; acc[7][tt] += wv * hB.w;                  \
        }                                                                      \
    }

__global__ __launch_bounds__(256) void epi_kernel(
    const float* __restrict__ x, const _Float16* __restrict__ h0,
    unsigned long long ASZ,
    const float* __restrict__ W_out, const float* __restrict__ b_out,
    const float* __restrict__ W_res, const float* __restrict__ b_res,
    const float* __restrict__ gamma, const float* __restrict__ beta,
    const float* __restrict__ mean, const float* __restrict__ var,
    const float* __restrict__ alpha_p, float* __restrict__ out, int n0)
{
    const int bx = blockIdx.x;
    const int v0 = (bx >> 3) * 32;
    const int t0 = (bx & 7) * 8;
    const int nl = blockIdx.y;
    const int ng = n0 + nl;
    const int tid = threadIdx.x;
    const int o = tid & 63;
    const int vg = tid >> 6;

    __shared__ __attribute__((aligned(16))) float sH[8][8][36];
    __shared__ float sW[8][64];

    const float rs = gamma[o] * rsqrtf(var[o] + 1e-5f);
    const float bias = b_out[o] + beta[o] + rs * (b_res[o] - mean[o]);
    float acc[8][8];
#pragma unroll
    for (int i = 0; i < 8; ++i)
#pragma unroll
        for (int j = 0; j < 8; ++j) acc[i][j] = bias;

    const int st = tid >> 5, sv = tid & 31;   // h-stage coords (t,v)
    const int rv = tid >> 3, rt = tid & 7;    // x-stage coords (v,t)

    for (int rd = 0; rd < 28; ++rd) {
        const int a = rd >> 2;
        const int cb = (rd & 3) * 8;
        const _Float16* hb = h0 + (size_t)a * ASZ
            + ((size_t)((nl * C_ + cb) * T_) + t0 + st) * V_ + v0 + sv;
#pragma unroll
        for (int c = 0; c < 8; ++c)
            sH[c][st][sv] = (float)hb[(size_t)c * TV_];
#pragma unroll
        for (int k = 0; k < 2; ++k) {
            int lin = k * 256 + tid;
            int c = lin >> 6, oo = lin & 63;
            sW[c][oo] = W_out[oo * GCIN_ + a * 32 + cb + c];
        }
        __syncthreads();
        EPI_COMPUTE();
        __syncthreads();
    }

    for (int cr = 0; cr < 4; ++cr) {
        const int cb = cr * 8;
        const float* xb = x + ((size_t)(ng * C_ + cb) * V_ + v0 + rv) * T_ + t0 + rt;
#pragma unroll
        for (int c = 0; c < 8; ++c)
            sH[c][rt][rv] = xb[(size_t)c * (V_ * T_)];
#pragma unroll
        for (int k = 0; k < 2; ++k) {
            int lin = k * 256 + tid;
            int c = lin >> 6, oo = lin & 63;
            float rs2 = gamma[oo] * rsqrtf(var[oo] + 1e-5f);
            sW[c][oo] = rs2 * W_res[oo * C_ + cb + c];
        }
        __syncthreads();
        EPI_COMPUTE();
        __syncthreads();
    }

    const float al = alpha_p[0];
    float* ob = out + ((size_t)(ng * OC_ + o) * V_ + v0 + vg * 8) * T_ + t0;
#pragma unroll
    for (int vv = 0; vv < 8; ++vv) {
#pragma unroll
        for (int tt = 0; tt < 8; ++tt) {
            float u = acc[vv][tt];
            acc[vv][tt] = u > 0.f ? u : al * u;
        }
        *(float4*)&ob[(size_t)vv * T_] =
            make_float4(acc[vv][0], acc[vv][1], acc[vv][2], acc[vv][3]);
        *(float4*)&ob[(size_t)vv * T_ + 4] =
            make_float4(acc[vv][4], acc[vv][5], acc[vv][6], acc[vv][7]);
    }
}

// ---------------------------------------------------------------------------
extern "C" void kernel_launch(void* const* d_in, const int* in_sizes, int n_in,
                              void* d_out, int out_size, void* d_ws, size_t ws_size,
                              hipStream_t stream)
{
    const float* x       = (const float*)d_in[0];
    const float* t_in    = (const float*)d_in[1];
    const float* A0      = (const float*)d_in[2];
    const float* A1      = (const float*)d_in[3];
    const float* A2      = (const float*)d_in[4];
    const float* factors = (const float*)d_in[5];
    const float* Wq      = (const float*)d_in[6];
    const float* Wk      = (const float*)d_in[7];
    const float* W_out   = (const float*)d_in[8];
    const float* b_out   = (const float*)d_in[9];
    const float* W_res   = (const float*)d_in[10];
    const float* b_res   = (const float*)d_in[11];
    const float* gamma   = (const float*)d_in[12];
    const float* beta    = (const float*)d_in[13];
    const float* mean    = (const float*)d_in[14];
    const float* var     = (const float*)d_in[15];
    const float* alpha   = (const float*)d_in[16];
    float* out = (float*)d_out;

    float* att = (float*)d_ws;                              // 262144 f32
    float* S   = att + (size_t)N_ * H_ * T_ * T_;           // 65536 f32
    _Float16* At16 = (_Float16*)(S + (size_t)N_ * T_ * T_); // 3*V*V f16
    _Float16* h0 = At16 + (size_t)3 * V_ * V_;              // 7 chunk arrays

    const size_t fixed = ((size_t)N_ * H_ * T_ * T_ + (size_t)N_ * T_ * T_) * 4
                       + (size_t)3 * V_ * V_ * 2;
    int Nc = 16;
    while (Nc > 1 && fixed + (size_t)7 * Nc * C_ * T_ * V_ * 2 > ws_size) Nc >>= 1;
    const size_t ASZ = (size_t)Nc * C_ * T_ * V_;   // elements per chunk array

    att_kernel<<<N_ * H_, 64, 0, stream>>>(t_in, factors, Wq, Wk, att);
    sred_kernel<<<(N_ * T_ * T_ + 255) / 256, 256, 0, stream>>>(att, S);
    prepAt_kernel<<<dim3(16, 16, 3), 256, 0, stream>>>(A0, A1, A2, At16);

    for (int n0 = 0; n0 < N_; n0 += Nc) {
        const int nsl = Nc * C_;
        xtT_kernel<<<dim3(2, nsl), 256, 0, stream>>>(x, S, h0, n0);
        for (int s = 0; s < 3; ++s) {
            const _Float16* Ats = At16 + (size_t)s * V_ * V_;
            _Float16* x1 = h0 + (size_t)(1 + 2 * s) * ASZ;
            _Float16* x2 = h0 + (size_t)(2 + 2 * s) * ASZ;
            hop_kernel<<<dim3(2, nsl), 256, 0, stream>>>(Ats, h0, x1);
            hop_kernel<<<dim3(2, nsl), 256, 0, stream>>>(Ats, x1, x2);
        }
        epi_kernel<<<dim3(128, Nc), 256, 0, stream>>>(
            x, h0, (unsigned long long)ASZ, W_out, b_out, W_res, b_res,
            gamma, beta, mean, var, alpha, out, n0);
    }
}

// Round 3
// 684.082 us; speedup vs baseline: 2.5068x; 1.6930x over previous
//
#include <hip/hip_runtime.h>

namespace {
constexpr int N_ = 16, C_ = 32, V_ = 512, T_ = 64;
constexpr int H_ = 4, D_ = 16, OC_ = 64;
constexpr int EMB_ = 64;
constexpr int GCIN_ = 7 * C_;         // 224
constexpr int TV_ = T_ * V_;          // 32768 (one slice, [t][v] f16 layout)
}

typedef _Float16 f16x8 __attribute__((ext_vector_type(8)));
typedef _Float16 f16x4 __attribute__((ext_vector_type(4)));
typedef float f32x4 __attribute__((ext_vector_type(4)));

// ---------------------------------------------------------------------------
// Kernel 1: per-(n,h) attention rows. att[n,h,t,p] = softmax_p(q_t . k_p / 4)
// ---------------------------------------------------------------------------
__global__ __launch_bounds__(64) void att_kernel(
    const float* __restrict__ t_in, const float* __restrict__ factors,
    const float* __restrict__ Wq, const float* __restrict__ Wk,
    float* __restrict__ att)
{
    const int n = blockIdx.x >> 2;
    const int h = blockIdx.x & 3;
    const int t = threadIdx.x;   // 0..63

    __shared__ float wq_l[EMB_][D_];
    __shared__ float wk_l[EMB_][D_];
    __shared__ float k_l[T_][D_ + 1];

#pragma unroll
    for (int d = 0; d < D_; ++d) {
        wq_l[t][d] = Wq[(h * EMB_ + t) * D_ + d];
        wk_l[t][d] = Wk[(h * EMB_ + t) * D_ + d];
    }
    __syncthreads();

    const float tv = t_in[n * T_ + t];
    const float fh = factors[h];
    float emb[EMB_];
#pragma unroll
    for (int j = 0; j < 32; ++j) {
        float dt = __expf((float)(2 * j) * fh);
        float ph = tv * dt;
        float s, c;
        __sincosf(ph, &s, &c);
        emb[j] = s;
        emb[j + 32] = c;
    }

    float q[D_];
#pragma unroll
    for (int d = 0; d < D_; ++d) {
        float aq = 0.f, ak = 0.f;
#pragma unroll
        for (int f = 0; f < EMB_; ++f) {
            aq += emb[f] * wq_l[f][d];
            ak += emb[f] * wk_l[f][d];
        }
        q[d] = aq;
        k_l[t][d] = ak;
    }
    __syncthreads();

    float L[T_];
    float m = -1e30f;
#pragma unroll
    for (int j = 0; j < T_; ++j) {
        float a = 0.f;
#pragma unroll
        for (int d = 0; d < D_; ++d) a += q[d] * k_l[j][d];
        a *= 0.25f;
        L[j] = a;
        m = fmaxf(m, a);
    }
    float ssum = 0.f;
#pragma unroll
    for (int j = 0; j < T_; ++j) {
        float e = __expf(L[j] - m);
        L[j] = e;
        ssum += e;
    }
    const float inv = 1.f / ssum;
    float* arow = att + (((size_t)(n * H_ + h) * T_ + t) * T_);
#pragma unroll
    for (int j = 0; j < T_; ++j) arow[j] = L[j] * inv;
}

// ---------------------------------------------------------------------------
// Kernel 2: S[n,i,j] = sum_h att[n,h,i,j]
// ---------------------------------------------------------------------------
__global__ __launch_bounds__(256) void sred_kernel(
    const float* __restrict__ att, float* __restrict__ S)
{
    int g = blockIdx.x * 256 + threadIdx.x;
    if (g >= N_ * T_ * T_) return;
    int n = g / (T_ * T_);
    int ij = g - n * (T_ * T_);
    float a = 0.f;
#pragma unroll
    for (int h = 0; h < H_; ++h) a += att[(size_t)(n * H_ + h) * (T_ * T_) + ij];
    S[g] = a;
}

// ---------------------------------------------------------------------------
// Kernel 3: At16[s][w][v] = (f16) A_s[v][w]   (transpose + cast)
// ---------------------------------------------------------------------------
__global__ __launch_bounds__(256) void prepAt_kernel(
    const float* __restrict__ A0, const float* __restrict__ A1,
    const float* __restrict__ A2, _Float16* __restrict__ At16)
{
    const int s = blockIdx.z;
    const float* A = (s == 0) ? A0 : ((s == 1) ? A1 : A2);
    const int v0 = blockIdx.y * 32, w0 = blockIdx.x * 32;
    const int tid = threadIdx.x;
    __shared__ float sT[32][33];
#pragma unroll
    for (int k = 0; k < 4; ++k) {
        int lin = k * 256 + tid;
        int i = lin >> 5, w = lin & 31;
        sT[i][w] = A[(size_t)(v0 + i) * V_ + w0 + w];
    }
    __syncthreads();
#pragma unroll
    for (int k = 0; k < 4; ++k) {
        int lin = k * 256 + tid;
        int j = lin >> 5, i = lin & 31;
        At16[(size_t)s * V_ * V_ + (size_t)(w0 + j) * V_ + v0 + i] = (_Float16)sT[i][j];
    }
}

// ---------------------------------------------------------------------------
// Kernel 3b: xT16[b][t][v] = (f16) x[n0*C + b][v][t]  (residual channels)
// ---------------------------------------------------------------------------
__global__ __launch_bounds__(256) void prepxT_kernel(
    const float* __restrict__ x, _Float16* __restrict__ xT, int n0)
{
    const int b = blockIdx.z;
    const int v0 = blockIdx.x * 32;
    const int t0 = blockIdx.y * 32;
    const int tid = threadIdx.x;
    __shared__ float sT[32][33];
    const float* xb = x + ((size_t)(n0 * C_) + b) * (size_t)(V_ * T_);
    {
        int vi = tid >> 3, tq = tid & 7;
        *(float4*)&sT[vi][tq * 4] = *(const float4*)&xb[(size_t)(v0 + vi) * T_ + t0 + tq * 4];
    }
    __syncthreads();
    {
        int tj = tid >> 3, vq = tid & 7;
        f16x4 o4;
        o4[0] = (_Float16)sT[vq * 4 + 0][tj];
        o4[1] = (_Float16)sT[vq * 4 + 1][tj];
        o4[2] = (_Float16)sT[vq * 4 + 2][tj];
        o4[3] = (_Float16)sT[vq * 4 + 3][tj];
        *(f16x4*)&xT[(size_t)b * TV_ + (size_t)(t0 + tj) * V_ + v0 + vq * 4] = o4;
    }
}

// ---------------------------------------------------------------------------
// Kernel 3c: Wcat[o][k] f16 (k<224: W_out; k>=224: BN-scaled W_res), bias[o].
// ---------------------------------------------------------------------------
__global__ __launch_bounds__(256) void prepW_kernel(
    const float* __restrict__ W_out, const float* __restrict__ b_out,
    const float* __restrict__ W_res, const float* __restrict__ b_res,
    const float* __restrict__ gamma, const float* __restrict__ beta,
    const float* __restrict__ mean, const float* __restrict__ var,
    _Float16* __restrict__ Wcat, float* __restrict__ bias)
{
    const int tid = threadIdx.x;
    const int o = tid & 63;
    const int kb = tid >> 6;   // 0..3
    const float rs = gamma[o] * rsqrtf(var[o] + 1e-5f);
    for (int kk = 0; kk < 64; ++kk) {
        int k = kb * 64 + kk;
        float w = (k < GCIN_) ? W_out[o * GCIN_ + k] : rs * W_res[o * C_ + (k - GCIN_)];
        Wcat[o * 256 + k] = (_Float16)w;
    }
    if (tid < 64) bias[tid] = b_out[tid] + beta[tid] + rs * (b_res[tid] - mean[tid]);
}

// ---------------------------------------------------------------------------
// Kernel 4: xtT[b][p][v] = sum_j S[n][p][j] * x[b][v][j]   (f16 out, MFMA)
// ---------------------------------------------------------------------------
__global__ __launch_bounds__(256) void xtT_kernel(
    const float* __restrict__ x, const float* __restrict__ S,
    _Float16* __restrict__ XT, int n0)
{
    const int b = blockIdx.y;
    const int n = n0 + b / C_;
    const int lane = threadIdx.x & 63;
    const int wav = threadIdx.x >> 6;
    const int vbase = blockIdx.x * 256 + wav * 64;
    const int row16 = lane & 15;
    const int kg = lane >> 4;

    const float* Sn = S + (size_t)n * (T_ * T_);
    const float* xb = x + ((size_t)(n0 * C_) + b) * (V_ * T_);

    f32x4 acc[4][4];
#pragma unroll
    for (int i = 0; i < 4; ++i)
#pragma unroll
        for (int j = 0; j < 4; ++j) acc[i][j] = (f32x4){0.f, 0.f, 0.f, 0.f};

#pragma unroll
    for (int ks = 0; ks < 2; ++ks) {
        f16x8 a[4], bf[4];
#pragma unroll
        for (int mt = 0; mt < 4; ++mt) {
            const float* p = Sn + (size_t)(mt * 16 + row16) * T_ + ks * 32 + kg * 8;
            float4 u = *(const float4*)p;
            float4 w = *(const float4*)(p + 4);
            f16x8 t8;
            t8[0] = (_Float16)u.x; t8[1] = (_Float16)u.y; t8[2] = (_Float16)u.z; t8[3] = (_Float16)u.w;
            t8[4] = (_Float16)w.x; t8[5] = (_Float16)w.y; t8[6] = (_Float16)w.z; t8[7] = (_Float16)w.w;
            a[mt] = t8;
        }
#pragma unroll
        for (int nt = 0; nt < 4; ++nt) {
            const float* p = xb + (size_t)(vbase + nt * 16 + row16) * T_ + ks * 32 + kg * 8;
            float4 u = *(const float4*)p;
            float4 w = *(const float4*)(p + 4);
            f16x8 t8;
            t8[0] = (_Float16)u.x; t8[1] = (_Float16)u.y; t8[2] = (_Float16)u.z; t8[3] = (_Float16)u.w;
            t8[4] = (_Float16)w.x; t8[5] = (_Float16)w.y; t8[6] = (_Float16)w.z; t8[7] = (_Float16)w.w;
            bf[nt] = t8;
        }
#pragma unroll
        for (int nt = 0; nt < 4; ++nt)
#pragma unroll
            for (int mt = 0; mt < 4; ++mt)
                acc[mt][nt] = __builtin_amdgcn_mfma_f32_16x16x32_f16(a[mt], bf[nt], acc[mt][nt], 0, 0, 0);
    }

    _Float16* Yb = XT + (size_t)b * TV_;
#pragma unroll
    for (int mt = 0; mt < 4; ++mt)
#pragma unroll
        for (int nt = 0; nt < 4; ++nt)
#pragma unroll
            for (int r = 0; r < 4; ++r) {
                int t = mt * 16 + kg * 4 + r;
                int v = vbase + nt * 16 + row16;
                Yb[(size_t)t * V_ + v] = (_Float16)acc[mt][nt][r];
            }
}

// ---------------------------------------------------------------------------
// Kernel 5: diffusion hop  Y[b][t][w] = sum_v X[b][t][v] * At16[w][v]
// ---------------------------------------------------------------------------
__global__ __launch_bounds__(256) void hop_kernel(
    const _Float16* __restrict__ At, const _Float16* __restrict__ X,
    _Float16* __restrict__ Y)
{
    const int b = blockIdx.y;
    const int lane = threadIdx.x & 63;
    const int wav = threadIdx.x >> 6;
    const int wbase = blockIdx.x * 256 + wav * 64;
    const int row16 = lane & 15;
    const int kg = lane >> 4;

    const _Float16* Xb = X + (size_t)b * TV_;
    const _Float16* ax = Xb + (size_t)row16 * V_ + kg * 8;
    const _Float16* bx = At + (size_t)(wbase + row16) * V_ + kg * 8;

    f32x4 acc[4][4];
#pragma unroll
    for (int i = 0; i < 4; ++i)
#pragma unroll
        for (int j = 0; j < 4; ++j) acc[i][j] = (f32x4){0.f, 0.f, 0.f, 0.f};

    for (int v0 = 0; v0 < V_; v0 += 32) {
        f16x8 a[4], bf[4];
#pragma unroll
        for (int mt = 0; mt < 4; ++mt)
            a[mt] = *(const f16x8*)(ax + (size_t)mt * 16 * V_ + v0);
#pragma unroll
        for (int nt = 0; nt < 4; ++nt)
            bf[nt] = *(const f16x8*)(bx + (size_t)nt * 16 * V_ + v0);
#pragma unroll
        for (int nt = 0; nt < 4; ++nt)
#pragma unroll
            for (int mt = 0; mt < 4; ++mt)
                acc[mt][nt] = __builtin_amdgcn_mfma_f32_16x16x32_f16(a[mt], bf[nt], acc[mt][nt], 0, 0, 0);
    }

    _Float16* Yb = Y + (size_t)b * TV_;
#pragma unroll
    for (int mt = 0; mt < 4; ++mt)
#pragma unroll
        for (int nt = 0; nt < 4; ++nt)
#pragma unroll
            for (int r = 0; r < 4; ++r) {
                int t = mt * 16 + kg * 4 + r;
                int w = wbase + nt * 16 + row16;
                Yb[(size_t)t * V_ + w] = (_Float16)acc[mt][nt][r];
            }
}

// ---------------------------------------------------------------------------
// Kernel 6: MFMA epilogue GEMM.
// out[ng,o,v,t] = PReLU( bias[o] + sum_{k=0..255} Wcat[o,k] * H_k[nl][t][v] )
// Block: 16 v x 16 t x all 64 o. Wave w handles t = t0 + w*4 + (0..3).
// K-chunk ks covers exactly H array #ks (channels kg*8+e).
// ---------------------------------------------------------------------------
__global__ __launch_bounds__(256) void epi_kernel(
    const _Float16* __restrict__ H, unsigned long long ASZ,
    const _Float16* __restrict__ Wcat, const float* __restrict__ bias,
    const float* __restrict__ alpha_p, float* __restrict__ out, int n0)
{
    const int v0 = blockIdx.x * 16;
    const int t0 = blockIdx.y * 16;
    const int nl = blockIdx.z;
    const int ng = n0 + nl;
    const int tid = threadIdx.x;
    const int lane = tid & 63;
    const int w = tid >> 6;
    const int row16 = lane & 15;
    const int kg = lane >> 4;

    f32x4 acc[4][4];   // [j: t-offset][mt: o-tile]
#pragma unroll
    for (int i = 0; i < 4; ++i)
#pragma unroll
        for (int j = 0; j < 4; ++j) acc[i][j] = (f32x4){0.f, 0.f, 0.f, 0.f};

    const int pbase = (nl * C_ + kg * 8) * TV_ + (t0 + w * 4) * V_ + v0 + row16;

#pragma unroll
    for (int ks = 0; ks < 8; ++ks) {
        const _Float16* Hk = H + (size_t)ks * ASZ;
        f16x8 a[4];
#pragma unroll
        for (int mt = 0; mt < 4; ++mt)
            a[mt] = *(const f16x8*)(Wcat + (mt * 16 + row16) * 256 + ks * 32 + kg * 8);
#pragma unroll
        for (int j = 0; j < 4; ++j) {
            const _Float16* hp = Hk + pbase + j * V_;
            f16x8 bf;
#pragma unroll
            for (int e = 0; e < 8; ++e) bf[e] = hp[e * TV_];
#pragma unroll
            for (int mt = 0; mt < 4; ++mt)
                acc[j][mt] = __builtin_amdgcn_mfma_f32_16x16x32_f16(a[mt], bf, acc[j][mt], 0, 0, 0);
        }
    }

    // C-tile transpose via LDS: addr = o'*289 + v*17 + t  (<=2-way conflicts)
    __shared__ float sC[16 * 289];
    const float al = alpha_p[0];
    const int ot = tid >> 4;
    const int vv = tid & 15;

    for (int mt = 0; mt < 4; ++mt) {
#pragma unroll
        for (int j = 0; j < 4; ++j)
#pragma unroll
            for (int r = 0; r < 4; ++r)
                sC[(kg * 4 + r) * 289 + row16 * 17 + (w * 4 + j)] = acc[j][mt][r];
        __syncthreads();
        const float bo = bias[mt * 16 + ot];
        float vals[16];
#pragma unroll
        for (int tt = 0; tt < 16; ++tt) {
            float u = sC[ot * 289 + vv * 17 + tt] + bo;
            vals[tt] = u > 0.f ? u : al * u;
        }
        float* op = out + (((size_t)ng * OC_ + mt * 16 + ot) * V_ + v0 + vv) * T_ + t0;
        *(float4*)&op[0]  = make_float4(vals[0], vals[1], vals[2], vals[3]);
        *(float4*)&op[4]  = make_float4(vals[4], vals[5], vals[6], vals[7]);
        *(float4*)&op[8]  = make_float4(vals[8], vals[9], vals[10], vals[11]);
        *(float4*)&op[12] = make_float4(vals[12], vals[13], vals[14], vals[15]);
        __syncthreads();
    }
}

// ---------------------------------------------------------------------------
extern "C" void kernel_launch(void* const* d_in, const int* in_sizes, int n_in,
                              void* d_out, int out_size, void* d_ws, size_t ws_size,
                              hipStream_t stream)
{
    const float* x       = (const float*)d_in[0];
    const float* t_in    = (const float*)d_in[1];
    const float* A0      = (const float*)d_in[2];
    const float* A1      = (const float*)d_in[3];
    const float* A2      = (const float*)d_in[4];
    const float* factors = (const float*)d_in[5];
    const float* Wq      = (const float*)d_in[6];
    const float* Wk      = (const float*)d_in[7];
    const float* W_out   = (const float*)d_in[8];
    const float* b_out   = (const float*)d_in[9];
    const float* W_res   = (const float*)d_in[10];
    const float* b_res   = (const float*)d_in[11];
    const float* gamma   = (const float*)d_in[12];
    const float* beta    = (const float*)d_in[13];
    const float* mean    = (const float*)d_in[14];
    const float* var     = (const float*)d_in[15];
    const float* alpha   = (const float*)d_in[16];
    float* out = (float*)d_out;

    float* att = (float*)d_ws;                               // 262144 f32
    float* S    = att + (size_t)N_ * H_ * T_ * T_;           // 65536 f32
    float* bias = S + (size_t)N_ * T_ * T_;                  // 64 f32
    _Float16* At16 = (_Float16*)(bias + 64);                 // 3*V*V f16
    _Float16* Wcat = At16 + (size_t)3 * V_ * V_;             // 64*256 f16
    _Float16* Hbase = Wcat + (size_t)64 * 256;               // 8 chunk arrays

    const size_t fixed = ((size_t)N_ * H_ * T_ * T_ + (size_t)N_ * T_ * T_ + 64) * 4
                       + ((size_t)3 * V_ * V_ + 64 * 256) * 2;
    int Nc = 16;
    while (Nc > 1 && fixed + (size_t)8 * Nc * C_ * T_ * V_ * 2 > ws_size) Nc >>= 1;
    const size_t ASZ = (size_t)Nc * C_ * T_ * V_;   // elements per chunk array

    att_kernel<<<N_ * H_, 64, 0, stream>>>(t_in, factors, Wq, Wk, att);
    sred_kernel<<<(N_ * T_ * T_ + 255) / 256, 256, 0, stream>>>(att, S);
    prepAt_kernel<<<dim3(16, 16, 3), 256, 0, stream>>>(A0, A1, A2, At16);
    prepW_kernel<<<1, 256, 0, stream>>>(W_out, b_out, W_res, b_res,
                                        gamma, beta, mean, var, Wcat, bias);

    for (int n0 = 0; n0 < N_; n0 += Nc) {
        const int nsl = Nc * C_;
        xtT_kernel<<<dim3(2, nsl), 256, 0, stream>>>(x, S, Hbase, n0);
        prepxT_kernel<<<dim3(16, 2, nsl), 256, 0, stream>>>(x, Hbase + (size_t)7 * ASZ, n0);
        for (int s = 0; s < 3; ++s) {
            const _Float16* Ats = At16 + (size_t)s * V_ * V_;
            _Float16* x1 = Hbase + (size_t)(1 + 2 * s) * ASZ;
            _Float16* x2 = Hbase + (size_t)(2 + 2 * s) * ASZ;
            hop_kernel<<<dim3(2, nsl), 256, 0, stream>>>(Ats, Hbase, x1);
            hop_kernel<<<dim3(2, nsl), 256, 0, stream>>>(Ats, x1, x2);
        }
        epi_kernel<<<dim3(32, 4, Nc), 256, 0, stream>>>(
            Hbase, (unsigned long long)ASZ, Wcat, bias, alpha, out, n0);
    }
}

// Round 4
// 566.394 us; speedup vs baseline: 3.0277x; 1.2078x over previous
//
#include <hip/hip_runtime.h>

namespace {
constexpr int N_ = 16, C_ = 32, V_ = 512, T_ = 64;
constexpr int H_ = 4, D_ = 16, OC_ = 64;
constexpr int EMB_ = 64;
constexpr int GCIN_ = 7 * C_;         // 224
constexpr int TV_ = T_ * V_;          // 32768 (one slice, [t][v] f16 layout)
}

typedef _Float16 f16x8 __attribute__((ext_vector_type(8)));
typedef _Float16 f16x4 __attribute__((ext_vector_type(4)));
typedef float f32x4 __attribute__((ext_vector_type(4)));

// ---------------------------------------------------------------------------
// Kernel 1: per-(n,h) attention rows. att[n,h,t,p] = softmax_p(q_t . k_p / 4)
// ---------------------------------------------------------------------------
__global__ __launch_bounds__(64) void att_kernel(
    const float* __restrict__ t_in, const float* __restrict__ factors,
    const float* __restrict__ Wq, const float* __restrict__ Wk,
    float* __restrict__ att)
{
    const int n = blockIdx.x >> 2;
    const int h = blockIdx.x & 3;
    const int t = threadIdx.x;   // 0..63

    __shared__ float wq_l[EMB_][D_];
    __shared__ float wk_l[EMB_][D_];
    __shared__ float k_l[T_][D_ + 1];

#pragma unroll
    for (int d = 0; d < D_; ++d) {
        wq_l[t][d] = Wq[(h * EMB_ + t) * D_ + d];
        wk_l[t][d] = Wk[(h * EMB_ + t) * D_ + d];
    }
    __syncthreads();

    const float tv = t_in[n * T_ + t];
    const float fh = factors[h];
    float emb[EMB_];
#pragma unroll
    for (int j = 0; j < 32; ++j) {
        float dt = __expf((float)(2 * j) * fh);
        float ph = tv * dt;
        float s, c;
        __sincosf(ph, &s, &c);
        emb[j] = s;
        emb[j + 32] = c;
    }

    float q[D_];
#pragma unroll
    for (int d = 0; d < D_; ++d) {
        float aq = 0.f, ak = 0.f;
#pragma unroll
        for (int f = 0; f < EMB_; ++f) {
            aq += emb[f] * wq_l[f][d];
            ak += emb[f] * wk_l[f][d];
        }
        q[d] = aq;
        k_l[t][d] = ak;
    }
    __syncthreads();

    float L[T_];
    float m = -1e30f;
#pragma unroll
    for (int j = 0; j < T_; ++j) {
        float a = 0.f;
#pragma unroll
        for (int d = 0; d < D_; ++d) a += q[d] * k_l[j][d];
        a *= 0.25f;
        L[j] = a;
        m = fmaxf(m, a);
    }
    float ssum = 0.f;
#pragma unroll
    for (int j = 0; j < T_; ++j) {
        float e = __expf(L[j] - m);
        L[j] = e;
        ssum += e;
    }
    const float inv = 1.f / ssum;
    float* arow = att + (((size_t)(n * H_ + h) * T_ + t) * T_);
#pragma unroll
    for (int j = 0; j < T_; ++j) arow[j] = L[j] * inv;
}

// ---------------------------------------------------------------------------
// Kernel 2: S[n,i,j] = sum_h att[n,h,i,j]
// ---------------------------------------------------------------------------
__global__ __launch_bounds__(256) void sred_kernel(
    const float* __restrict__ att, float* __restrict__ S)
{
    int g = blockIdx.x * 256 + threadIdx.x;
    if (g >= N_ * T_ * T_) return;
    int n = g / (T_ * T_);
    int ij = g - n * (T_ * T_);
    float a = 0.f;
#pragma unroll
    for (int h = 0; h < H_; ++h) a += att[(size_t)(n * H_ + h) * (T_ * T_) + ij];
    S[g] = a;
}

// ---------------------------------------------------------------------------
// Kernel 3: At16[s][w][v] = (f16) A_s[v][w]   (transpose + cast)
// ---------------------------------------------------------------------------
__global__ __launch_bounds__(256) void prepAt_kernel(
    const float* __restrict__ A0, const float* __restrict__ A1,
    const float* __restrict__ A2, _Float16* __restrict__ At16)
{
    const int s = blockIdx.z;
    const float* A = (s == 0) ? A0 : ((s == 1) ? A1 : A2);
    const int v0 = blockIdx.y * 32, w0 = blockIdx.x * 32;
    const int tid = threadIdx.x;
    __shared__ float sT[32][33];
#pragma unroll
    for (int k = 0; k < 4; ++k) {
        int lin = k * 256 + tid;
        int i = lin >> 5, w = lin & 31;
        sT[i][w] = A[(size_t)(v0 + i) * V_ + w0 + w];
    }
    __syncthreads();
#pragma unroll
    for (int k = 0; k < 4; ++k) {
        int lin = k * 256 + tid;
        int j = lin >> 5, i = lin & 31;
        At16[(size_t)s * V_ * V_ + (size_t)(w0 + j) * V_ + v0 + i] = (_Float16)sT[i][j];
    }
}

// ---------------------------------------------------------------------------
// Kernel 3b: xT16[b][t][v] = (f16) x[n0*C + b][v][t]  (residual channels)
// ---------------------------------------------------------------------------
__global__ __launch_bounds__(256) void prepxT_kernel(
    const float* __restrict__ x, _Float16* __restrict__ xT, int n0)
{
    const int b = blockIdx.z;
    const int v0 = blockIdx.x * 32;
    const int t0 = blockIdx.y * 32;
    const int tid = threadIdx.x;
    __shared__ float sT[32][33];
    const float* xb = x + ((size_t)(n0 * C_) + b) * (size_t)(V_ * T_);
    {
        int vi = tid >> 3, tq = tid & 7;
        *(float4*)&sT[vi][tq * 4] = *(const float4*)&xb[(size_t)(v0 + vi) * T_ + t0 + tq * 4];
    }
    __syncthreads();
    {
        int tj = tid >> 3, vq = tid & 7;
        f16x4 o4;
        o4[0] = (_Float16)sT[vq * 4 + 0][tj];
        o4[1] = (_Float16)sT[vq * 4 + 1][tj];
        o4[2] = (_Float16)sT[vq * 4 + 2][tj];
        o4[3] = (_Float16)sT[vq * 4 + 3][tj];
        *(f16x4*)&xT[(size_t)b * TV_ + (size_t)(t0 + tj) * V_ + v0 + vq * 4] = o4;
    }
}

// ---------------------------------------------------------------------------
// Kernel 3c: Wcat[o][k] f16 (k<224: W_out; k>=224: BN-scaled W_res), bias[o].
// ---------------------------------------------------------------------------
__global__ __launch_bounds__(256) void prepW_kernel(
    const float* __restrict__ W_out, const float* __restrict__ b_out,
    const float* __restrict__ W_res, const float* __restrict__ b_res,
    const float* __restrict__ gamma, const float* __restrict__ beta,
    const float* __restrict__ mean, const float* __restrict__ var,
    _Float16* __restrict__ Wcat, float* __restrict__ bias)
{
    const int tid = threadIdx.x;
    const int o = tid & 63;
    const int kb = tid >> 6;   // 0..3
    const float rs = gamma[o] * rsqrtf(var[o] + 1e-5f);
    for (int kk = 0; kk < 64; ++kk) {
        int k = kb * 64 + kk;
        float w = (k < GCIN_) ? W_out[o * GCIN_ + k] : rs * W_res[o * C_ + (k - GCIN_)];
        Wcat[o * 256 + k] = (_Float16)w;
    }
    if (tid < 64) bias[tid] = b_out[tid] + beta[tid] + rs * (b_res[tid] - mean[tid]);
}

// ---------------------------------------------------------------------------
// Kernel 4: xtT[b][p][v] = sum_j S[n][p][j] * x[b][v][j]   (f16 out, MFMA)
// ---------------------------------------------------------------------------
__global__ __launch_bounds__(256) void xtT_kernel(
    const float* __restrict__ x, const float* __restrict__ S,
    _Float16* __restrict__ XT, int n0)
{
    const int b = blockIdx.y;
    const int n = n0 + b / C_;
    const int lane = threadIdx.x & 63;
    const int wav = threadIdx.x >> 6;
    const int vbase = blockIdx.x * 256 + wav * 64;
    const int row16 = lane & 15;
    const int kg = lane >> 4;

    const float* Sn = S + (size_t)n * (T_ * T_);
    const float* xb = x + ((size_t)(n0 * C_) + b) * (V_ * T_);

    f32x4 acc[4][4];
#pragma unroll
    for (int i = 0; i < 4; ++i)
#pragma unroll
        for (int j = 0; j < 4; ++j) acc[i][j] = (f32x4){0.f, 0.f, 0.f, 0.f};

#pragma unroll
    for (int ks = 0; ks < 2; ++ks) {
        f16x8 a[4], bf[4];
#pragma unroll
        for (int mt = 0; mt < 4; ++mt) {
            const float* p = Sn + (size_t)(mt * 16 + row16) * T_ + ks * 32 + kg * 8;
            float4 u = *(const float4*)p;
            float4 w = *(const float4*)(p + 4);
            f16x8 t8;
            t8[0] = (_Float16)u.x; t8[1] = (_Float16)u.y; t8[2] = (_Float16)u.z; t8[3] = (_Float16)u.w;
            t8[4] = (_Float16)w.x; t8[5] = (_Float16)w.y; t8[6] = (_Float16)w.z; t8[7] = (_Float16)w.w;
            a[mt] = t8;
        }
#pragma unroll
        for (int nt = 0; nt < 4; ++nt) {
            const float* p = xb + (size_t)(vbase + nt * 16 + row16) * T_ + ks * 32 + kg * 8;
            float4 u = *(const float4*)p;
            float4 w = *(const float4*)(p + 4);
            f16x8 t8;
            t8[0] = (_Float16)u.x; t8[1] = (_Float16)u.y; t8[2] = (_Float16)u.z; t8[3] = (_Float16)u.w;
            t8[4] = (_Float16)w.x; t8[5] = (_Float16)w.y; t8[6] = (_Float16)w.z; t8[7] = (_Float16)w.w;
            bf[nt] = t8;
        }
#pragma unroll
        for (int nt = 0; nt < 4; ++nt)
#pragma unroll
            for (int mt = 0; mt < 4; ++mt)
                acc[mt][nt] = __builtin_amdgcn_mfma_f32_16x16x32_f16(a[mt], bf[nt], acc[mt][nt], 0, 0, 0);
    }

    _Float16* Yb = XT + (size_t)b * TV_;
#pragma unroll
    for (int mt = 0; mt < 4; ++mt)
#pragma unroll
        for (int nt = 0; nt < 4; ++nt)
#pragma unroll
            for (int r = 0; r < 4; ++r) {
                int t = mt * 16 + kg * 4 + r;
                int v = vbase + nt * 16 + row16;
                Yb[(size_t)t * V_ + v] = (_Float16)acc[mt][nt][r];
            }
}

// ---------------------------------------------------------------------------
// Kernel 5: fused double diffusion hop for one (slice, support).
// x1 = X @ At^T  -> global (epi chunk) + LDS (swizzled)
// x2 = x1 @ At^T -> global (epi chunk)
// 512 threads = 8 waves; wave wav owns w-tile [wav*64, wav*64+64).
// LDS swizzle: byte ^= (t&7)<<4 breaks the 1024B-row-stride bank pattern.
// ---------------------------------------------------------------------------
__global__ __launch_bounds__(512, 4) void hopf_kernel(
    const _Float16* __restrict__ At16, _Float16* __restrict__ Hb,
    unsigned long long ASZ)
{
    const int b = blockIdx.x;   // slice (n,c)
    const int s = blockIdx.y;   // support
    const int tid = threadIdx.x;
    const int lane = tid & 63;
    const int wav = tid >> 6;
    const int wbase = wav * 64;
    const int row16 = lane & 15;
    const int kg = lane >> 4;

    __shared__ _Float16 x1s[T_ * V_];   // 64 KiB

    const _Float16* At = At16 + (size_t)s * V_ * V_;
    const _Float16* Xb = Hb + (size_t)b * TV_;
    _Float16* Y1 = Hb + (size_t)(1 + 2 * s) * ASZ + (size_t)b * TV_;
    _Float16* Y2 = Hb + (size_t)(2 + 2 * s) * ASZ + (size_t)b * TV_;

    const _Float16* ax = Xb + (size_t)row16 * V_ + kg * 8;
    const _Float16* bx = At + (size_t)(wbase + row16) * V_ + kg * 8;

    f32x4 acc[4][4];
#pragma unroll
    for (int i = 0; i < 4; ++i)
#pragma unroll
        for (int j = 0; j < 4; ++j) acc[i][j] = (f32x4){0.f, 0.f, 0.f, 0.f};

    for (int v0 = 0; v0 < V_; v0 += 32) {
        f16x8 a[4], bf[4];
#pragma unroll
        for (int mt = 0; mt < 4; ++mt)
            a[mt] = *(const f16x8*)(ax + (size_t)mt * 16 * V_ + v0);
#pragma unroll
        for (int nt = 0; nt < 4; ++nt)
            bf[nt] = *(const f16x8*)(bx + (size_t)nt * 16 * V_ + v0);
#pragma unroll
        for (int nt = 0; nt < 4; ++nt)
#pragma unroll
            for (int mt = 0; mt < 4; ++mt)
                acc[mt][nt] = __builtin_amdgcn_mfma_f32_16x16x32_f16(a[mt], bf[nt], acc[mt][nt], 0, 0, 0);
    }

#pragma unroll
    for (int mt = 0; mt < 4; ++mt)
#pragma unroll
        for (int nt = 0; nt < 4; ++nt)
#pragma unroll
            for (int r = 0; r < 4; ++r) {
                int t = mt * 16 + kg * 4 + r;
                int w = wbase + nt * 16 + row16;
                _Float16 val = (_Float16)acc[mt][nt][r];
                int byte = (t * V_ + w) * 2;
                *(_Float16*)((char*)x1s + (byte ^ ((t & 7) << 4))) = val;
                Y1[(size_t)t * V_ + w] = val;
            }
    __syncthreads();

#pragma unroll
    for (int i = 0; i < 4; ++i)
#pragma unroll
        for (int j = 0; j < 4; ++j) acc[i][j] = (f32x4){0.f, 0.f, 0.f, 0.f};

    const int axor = (row16 & 7) << 4;
    for (int v0 = 0; v0 < V_; v0 += 32) {
        f16x8 a[4], bf[4];
#pragma unroll
        for (int mt = 0; mt < 4; ++mt) {
            int byte = ((mt * 16 + row16) * V_ + v0 + kg * 8) * 2;
            a[mt] = *(const f16x8*)((const char*)x1s + (byte ^ axor));
        }
#pragma unroll
        for (int nt = 0; nt < 4; ++nt)
            bf[nt] = *(const f16x8*)(bx + (size_t)nt * 16 * V_ + v0);
#pragma unroll
        for (int nt = 0; nt < 4; ++nt)
#pragma unroll
            for (int mt = 0; mt < 4; ++mt)
                acc[mt][nt] = __builtin_amdgcn_mfma_f32_16x16x32_f16(a[mt], bf[nt], acc[mt][nt], 0, 0, 0);
    }

#pragma unroll
    for (int mt = 0; mt < 4; ++mt)
#pragma unroll
        for (int nt = 0; nt < 4; ++nt)
#pragma unroll
            for (int r = 0; r < 4; ++r) {
                int t = mt * 16 + kg * 4 + r;
                int w = wbase + nt * 16 + row16;
                Y2[(size_t)t * V_ + w] = (_Float16)acc[mt][nt][r];
            }
}

// ---------------------------------------------------------------------------
// Kernel 6: MFMA epilogue GEMM, 64o x 32v x 8t per block (full-sector reads).
// out[ng,o,v,t] = PReLU( bias[o] + sum_{k=0..255} Wcat[o,k] * H_k[nl][t][v] )
// ---------------------------------------------------------------------------
__global__ __launch_bounds__(256) void epi_kernel(
    const _Float16* __restrict__ H, unsigned long long ASZ,
    const _Float16* __restrict__ Wcat, const float* __restrict__ bias,
    const float* __restrict__ alpha_p, float* __restrict__ out, int n0)
{
    const int v0 = blockIdx.x * 32;
    const int t0 = blockIdx.y * 8;
    const int nl = blockIdx.z;
    const int ng = n0 + nl;
    const int tid = threadIdx.x;
    const int lane = tid & 63;
    const int wv = tid >> 6;      // wave 0..3 -> t pair
    const int row16 = lane & 15;
    const int kg = lane >> 4;

    f32x4 acc[2][2][4];           // [j: t][vs: v-half][mt: o-tile]
#pragma unroll
    for (int j = 0; j < 2; ++j)
#pragma unroll
        for (int vs = 0; vs < 2; ++vs)
#pragma unroll
            for (int mt = 0; mt < 4; ++mt) acc[j][vs][mt] = (f32x4){0.f, 0.f, 0.f, 0.f};

    const size_t pb = ((size_t)(nl * C_ + kg * 8)) * TV_
                    + (size_t)(t0 + wv * 2) * V_ + v0 + row16;

#pragma unroll
    for (int ks = 0; ks < 8; ++ks) {
        const _Float16* Hk = H + (size_t)ks * ASZ;
        f16x8 a[4];
#pragma unroll
        for (int mt = 0; mt < 4; ++mt)
            a[mt] = *(const f16x8*)(Wcat + (mt * 16 + row16) * 256 + ks * 32 + kg * 8);
#pragma unroll
        for (int j = 0; j < 2; ++j)
#pragma unroll
            for (int vs = 0; vs < 2; ++vs) {
                const _Float16* hp = Hk + pb + (size_t)j * V_ + vs * 16;
                f16x8 bf;
#pragma unroll
                for (int e = 0; e < 8; ++e) bf[e] = hp[(size_t)e * TV_];
#pragma unroll
                for (int mt = 0; mt < 4; ++mt)
                    acc[j][vs][mt] = __builtin_amdgcn_mfma_f32_16x16x32_f16(a[mt], bf, acc[j][vs][mt], 0, 0, 0);
            }
    }

    // C transpose via LDS: sC[o16][v33-pad][t9-pad]
    __shared__ float sC[16 * 33 * 9];
    const float al = alpha_p[0];
    const int ot = tid >> 4;
    const int vvt = tid & 15;

    for (int mt = 0; mt < 4; ++mt) {
#pragma unroll
        for (int j = 0; j < 2; ++j)
#pragma unroll
            for (int vs = 0; vs < 2; ++vs)
#pragma unroll
                for (int r = 0; r < 4; ++r)
                    sC[((kg * 4 + r) * 33 + vs * 16 + row16) * 9 + wv * 2 + j] = acc[j][vs][mt][r];
        __syncthreads();
        const float bo = bias[mt * 16 + ot];
#pragma unroll
        for (int vh = 0; vh < 2; ++vh) {
            const int vl = vvt + vh * 16;
            float vals[8];
#pragma unroll
            for (int tt = 0; tt < 8; ++tt) {
                float u = sC[(ot * 33 + vl) * 9 + tt] + bo;
                vals[tt] = u > 0.f ? u : al * u;
            }
            float* op = out + (((size_t)ng * OC_ + mt * 16 + ot) * V_ + v0 + vl) * T_ + t0;
            *(float4*)&op[0] = make_float4(vals[0], vals[1], vals[2], vals[3]);
            *(float4*)&op[4] = make_float4(vals[4], vals[5], vals[6], vals[7]);
        }
        __syncthreads();
    }
}

// ---------------------------------------------------------------------------
extern "C" void kernel_launch(void* const* d_in, const int* in_sizes, int n_in,
                              void* d_out, int out_size, void* d_ws, size_t ws_size,
                              hipStream_t stream)
{
    const float* x       = (const float*)d_in[0];
    const float* t_in    = (const float*)d_in[1];
    const float* A0      = (const float*)d_in[2];
    const float* A1      = (const float*)d_in[3];
    const float* A2      = (const float*)d_in[4];
    const float* factors = (const float*)d_in[5];
    const float* Wq      = (const float*)d_in[6];
    const float* Wk      = (const float*)d_in[7];
    const float* W_out   = (const float*)d_in[8];
    const float* b_out   = (const float*)d_in[9];
    const float* W_res   = (const float*)d_in[10];
    const float* b_res   = (const float*)d_in[11];
    const float* gamma   = (const float*)d_in[12];
    const float* beta    = (const float*)d_in[13];
    const float* mean    = (const float*)d_in[14];
    const float* var     = (const float*)d_in[15];
    const float* alpha   = (const float*)d_in[16];
    float* out = (float*)d_out;

    float* att = (float*)d_ws;                               // 262144 f32
    float* S    = att + (size_t)N_ * H_ * T_ * T_;           // 65536 f32
    float* bias = S + (size_t)N_ * T_ * T_;                  // 64 f32
    _Float16* At16 = (_Float16*)(bias + 64);                 // 3*V*V f16
    _Float16* Wcat = At16 + (size_t)3 * V_ * V_;             // 64*256 f16
    _Float16* Hbase = Wcat + (size_t)64 * 256;               // 8 chunk arrays

    const size_t fixed = ((size_t)N_ * H_ * T_ * T_ + (size_t)N_ * T_ * T_ + 64) * 4
                       + ((size_t)3 * V_ * V_ + 64 * 256) * 2;
    int Nc = 16;
    while (Nc > 1 && fixed + (size_t)8 * Nc * C_ * T_ * V_ * 2 > ws_size) Nc >>= 1;
    const size_t ASZ = (size_t)Nc * C_ * T_ * V_;   // elements per chunk array

    att_kernel<<<N_ * H_, 64, 0, stream>>>(t_in, factors, Wq, Wk, att);
    sred_kernel<<<(N_ * T_ * T_ + 255) / 256, 256, 0, stream>>>(att, S);
    prepAt_kernel<<<dim3(16, 16, 3), 256, 0, stream>>>(A0, A1, A2, At16);
    prepW_kernel<<<1, 256, 0, stream>>>(W_out, b_out, W_res, b_res,
                                        gamma, beta, mean, var, Wcat, bias);

    for (int n0 = 0; n0 < N_; n0 += Nc) {
        const int nsl = Nc * C_;
        xtT_kernel<<<dim3(2, nsl), 256, 0, stream>>>(x, S, Hbase, n0);
        prepxT_kernel<<<dim3(16, 2, nsl), 256, 0, stream>>>(x, Hbase + (size_t)7 * ASZ, n0);
        hopf_kernel<<<dim3(nsl, 3), 512, 0, stream>>>(At16, Hbase, (unsigned long long)ASZ);
        epi_kernel<<<dim3(16, 8, Nc), 256, 0, stream>>>(
            Hbase, (unsigned long long)ASZ, Wcat, bias, alpha, out, n0);
    }
}

// Round 5
// 557.326 us; speedup vs baseline: 3.0769x; 1.0163x over previous
//
#include <hip/hip_runtime.h>

namespace {
constexpr int N_ = 16, C_ = 32, V_ = 512, T_ = 64;
constexpr int H_ = 4, D_ = 16, OC_ = 64;
constexpr int EMB_ = 64;
constexpr int GCIN_ = 7 * C_;         // 224
constexpr int TV_ = T_ * V_;          // 32768 (one slice, [t][v] f16 layout)
}

typedef _Float16 f16x8 __attribute__((ext_vector_type(8)));
typedef _Float16 f16x4 __attribute__((ext_vector_type(4)));
typedef float f32x4 __attribute__((ext_vector_type(4)));

// ---------------------------------------------------------------------------
// Kernel 1: per-(n,h) attention rows. att[n,h,t,p] = softmax_p(q_t . k_p / 4)
// ---------------------------------------------------------------------------
__global__ __launch_bounds__(64) void att_kernel(
    const float* __restrict__ t_in, const float* __restrict__ factors,
    const float* __restrict__ Wq, const float* __restrict__ Wk,
    float* __restrict__ att)
{
    const int n = blockIdx.x >> 2;
    const int h = blockIdx.x & 3;
    const int t = threadIdx.x;   // 0..63

    __shared__ float wq_l[EMB_][D_];
    __shared__ float wk_l[EMB_][D_];
    __shared__ float k_l[T_][D_ + 1];

#pragma unroll
    for (int d = 0; d < D_; ++d) {
        wq_l[t][d] = Wq[(h * EMB_ + t) * D_ + d];
        wk_l[t][d] = Wk[(h * EMB_ + t) * D_ + d];
    }
    __syncthreads();

    const float tv = t_in[n * T_ + t];
    const float fh = factors[h];
    float emb[EMB_];
#pragma unroll
    for (int j = 0; j < 32; ++j) {
        float dt = __expf((float)(2 * j) * fh);
        float ph = tv * dt;
        float s, c;
        __sincosf(ph, &s, &c);
        emb[j] = s;
        emb[j + 32] = c;
    }

    float q[D_];
#pragma unroll
    for (int d = 0; d < D_; ++d) {
        float aq = 0.f, ak = 0.f;
#pragma unroll
        for (int f = 0; f < EMB_; ++f) {
            aq += emb[f] * wq_l[f][d];
            ak += emb[f] * wk_l[f][d];
        }
        q[d] = aq;
        k_l[t][d] = ak;
    }
    __syncthreads();

    float L[T_];
    float m = -1e30f;
#pragma unroll
    for (int j = 0; j < T_; ++j) {
        float a = 0.f;
#pragma unroll
        for (int d = 0; d < D_; ++d) a += q[d] * k_l[j][d];
        a *= 0.25f;
        L[j] = a;
        m = fmaxf(m, a);
    }
    float ssum = 0.f;
#pragma unroll
    for (int j = 0; j < T_; ++j) {
        float e = __expf(L[j] - m);
        L[j] = e;
        ssum += e;
    }
    const float inv = 1.f / ssum;
    float* arow = att + (((size_t)(n * H_ + h) * T_ + t) * T_);
#pragma unroll
    for (int j = 0; j < T_; ++j) arow[j] = L[j] * inv;
}

// ---------------------------------------------------------------------------
// Kernel 2: S[n,i,j] = sum_h att[n,h,i,j]
// ---------------------------------------------------------------------------
__global__ __launch_bounds__(256) void sred_kernel(
    const float* __restrict__ att, float* __restrict__ S)
{
    int g = blockIdx.x * 256 + threadIdx.x;
    if (g >= N_ * T_ * T_) return;
    int n = g / (T_ * T_);
    int ij = g - n * (T_ * T_);
    float a = 0.f;
#pragma unroll
    for (int h = 0; h < H_; ++h) a += att[(size_t)(n * H_ + h) * (T_ * T_) + ij];
    S[g] = a;
}

// ---------------------------------------------------------------------------
// Kernel 3: At16[s][w][v] = (f16) A_s[v][w]   (transpose + cast)
// ---------------------------------------------------------------------------
__global__ __launch_bounds__(256) void prepAt_kernel(
    const float* __restrict__ A0, const float* __restrict__ A1,
    const float* __restrict__ A2, _Float16* __restrict__ At16)
{
    const int s = blockIdx.z;
    const float* A = (s == 0) ? A0 : ((s == 1) ? A1 : A2);
    const int v0 = blockIdx.y * 32, w0 = blockIdx.x * 32;
    const int tid = threadIdx.x;
    __shared__ float sT[32][33];
#pragma unroll
    for (int k = 0; k < 4; ++k) {
        int lin = k * 256 + tid;
        int i = lin >> 5, w = lin & 31;
        sT[i][w] = A[(size_t)(v0 + i) * V_ + w0 + w];
    }
    __syncthreads();
#pragma unroll
    for (int k = 0; k < 4; ++k) {
        int lin = k * 256 + tid;
        int j = lin >> 5, i = lin & 31;
        At16[(size_t)s * V_ * V_ + (size_t)(w0 + j) * V_ + v0 + i] = (_Float16)sT[i][j];
    }
}

// ---------------------------------------------------------------------------
// Kernel 3b: xT16[b][t][v] = (f16) x[n0*C + b][v][t]  (residual channels)
// ---------------------------------------------------------------------------
__global__ __launch_bounds__(256) void prepxT_kernel(
    const float* __restrict__ x, _Float16* __restrict__ xT, int n0)
{
    const int b = blockIdx.z;
    const int v0 = blockIdx.x * 32;
    const int t0 = blockIdx.y * 32;
    const int tid = threadIdx.x;
    __shared__ float sT[32][33];
    const float* xb = x + ((size_t)(n0 * C_) + b) * (size_t)(V_ * T_);
    {
        int vi = tid >> 3, tq = tid & 7;
        *(float4*)&sT[vi][tq * 4] = *(const float4*)&xb[(size_t)(v0 + vi) * T_ + t0 + tq * 4];
    }
    __syncthreads();
    {
        int tj = tid >> 3, vq = tid & 7;
        f16x4 o4;
        o4[0] = (_Float16)sT[vq * 4 + 0][tj];
        o4[1] = (_Float16)sT[vq * 4 + 1][tj];
        o4[2] = (_Float16)sT[vq * 4 + 2][tj];
        o4[3] = (_Float16)sT[vq * 4 + 3][tj];
        *(f16x4*)&xT[(size_t)b * TV_ + (size_t)(t0 + tj) * V_ + v0 + vq * 4] = o4;
    }
}

// ---------------------------------------------------------------------------
// Kernel 3c: Wcat[o][k] f16 (k<224: W_out; k>=224: BN-scaled W_res), bias[o].
// ---------------------------------------------------------------------------
__global__ __launch_bounds__(256) void prepW_kernel(
    const float* __restrict__ W_out, const float* __restrict__ b_out,
    const float* __restrict__ W_res, const float* __restrict__ b_res,
    const float* __restrict__ gamma, const float* __restrict__ beta,
    const float* __restrict__ mean, const float* __restrict__ var,
    _Float16* __restrict__ Wcat, float* __restrict__ bias)
{
    const int tid = threadIdx.x;
    const int o = tid & 63;
    const int kb = tid >> 6;   // 0..3
    const float rs = gamma[o] * rsqrtf(var[o] + 1e-5f);
    for (int kk = 0; kk < 64; ++kk) {
        int k = kb * 64 + kk;
        float w = (k < GCIN_) ? W_out[o * GCIN_ + k] : rs * W_res[o * C_ + (k - GCIN_)];
        Wcat[o * 256 + k] = (_Float16)w;
    }
    if (tid < 64) bias[tid] = b_out[tid] + beta[tid] + rs * (b_res[tid] - mean[tid]);
}

// ---------------------------------------------------------------------------
// Kernel 4: xtT[b][p][v] = sum_j S[n][p][j] * x[b][v][j]   (f16 out, MFMA)
// Swapped roles: A = x v-rows (m=v), B = S rows (n=p). D[v][p]: lane holds
// 4 consecutive v at fixed p -> 8B vector stores into XT[p][v].
// ---------------------------------------------------------------------------
__global__ __launch_bounds__(256) void xtT_kernel(
    const float* __restrict__ x, const float* __restrict__ S,
    _Float16* __restrict__ XT, int n0)
{
    const int b = blockIdx.y;
    const int n = n0 + b / C_;
    const int lane = threadIdx.x & 63;
    const int wav = threadIdx.x >> 6;
    const int vbase = blockIdx.x * 256 + wav * 64;
    const int row16 = lane & 15;
    const int kg = lane >> 4;

    const float* Sn = S + (size_t)n * (T_ * T_);
    const float* xb = x + ((size_t)(n0 * C_) + b) * (V_ * T_);

    f32x4 acc[4][4];
#pragma unroll
    for (int i = 0; i < 4; ++i)
#pragma unroll
        for (int j = 0; j < 4; ++j) acc[i][j] = (f32x4){0.f, 0.f, 0.f, 0.f};

#pragma unroll
    for (int ks = 0; ks < 2; ++ks) {
        f16x8 a[4], bf[4];
#pragma unroll
        for (int mt = 0; mt < 4; ++mt) {   // A = x rows (m = v)
            const float* p = xb + (size_t)(vbase + mt * 16 + row16) * T_ + ks * 32 + kg * 8;
            float4 u = *(const float4*)p;
            float4 w = *(const float4*)(p + 4);
            f16x8 t8;
            t8[0] = (_Float16)u.x; t8[1] = (_Float16)u.y; t8[2] = (_Float16)u.z; t8[3] = (_Float16)u.w;
            t8[4] = (_Float16)w.x; t8[5] = (_Float16)w.y; t8[6] = (_Float16)w.z; t8[7] = (_Float16)w.w;
            a[mt] = t8;
        }
#pragma unroll
        for (int nt = 0; nt < 4; ++nt) {   // B = S rows (n = p)
            const float* p = Sn + (size_t)(nt * 16 + row16) * T_ + ks * 32 + kg * 8;
            float4 u = *(const float4*)p;
            float4 w = *(const float4*)(p + 4);
            f16x8 t8;
            t8[0] = (_Float16)u.x; t8[1] = (_Float16)u.y; t8[2] = (_Float16)u.z; t8[3] = (_Float16)u.w;
            t8[4] = (_Float16)w.x; t8[5] = (_Float16)w.y; t8[6] = (_Float16)w.z; t8[7] = (_Float16)w.w;
            bf[nt] = t8;
        }
#pragma unroll
        for (int nt = 0; nt < 4; ++nt)
#pragma unroll
            for (int mt = 0; mt < 4; ++mt)
                acc[mt][nt] = __builtin_amdgcn_mfma_f32_16x16x32_f16(a[mt], bf[nt], acc[mt][nt], 0, 0, 0);
    }

    _Float16* Yb = XT + (size_t)b * TV_;
#pragma unroll
    for (int mt = 0; mt < 4; ++mt)
#pragma unroll
        for (int nt = 0; nt < 4; ++nt) {
            int p = nt * 16 + row16;
            int v = vbase + mt * 16 + kg * 4;
            f16x4 h;
            h[0] = (_Float16)acc[mt][nt][0];
            h[1] = (_Float16)acc[mt][nt][1];
            h[2] = (_Float16)acc[mt][nt][2];
            h[3] = (_Float16)acc[mt][nt][3];
            *(f16x4*)&Yb[(size_t)p * V_ + v] = h;
        }
}

// ---------------------------------------------------------------------------
// Kernel 5: fused double diffusion hop for one (slice, support).
// Swapped roles: A = At w-rows (m=w), B = X t-rows (n=t).
// D[w][t]: lane holds 4 consecutive w at fixed t -> 8B ds_write_b64 into the
// swizzled LDS x1 tile; global Y1/Y2 written via LDS as 16B coalesced stores.
// LDS swizzle: byte ^= (t&7)<<4 (conflict-free on write, Y-copy, and B-read).
// ---------------------------------------------------------------------------
__global__ __launch_bounds__(512, 4) void hopf_kernel(
    const _Float16* __restrict__ At16, _Float16* __restrict__ Hb,
    unsigned long long ASZ)
{
    const int b = blockIdx.x;   // slice (n,c)
    const int s = blockIdx.y;   // support
    const int tid = threadIdx.x;
    const int lane = tid & 63;
    const int wav = tid >> 6;
    const int wbase = wav * 64;
    const int row16 = lane & 15;
    const int kg = lane >> 4;

    __shared__ _Float16 x1s[T_ * V_];   // 64 KiB

    const _Float16* At = At16 + (size_t)s * V_ * V_;
    const _Float16* Xb = Hb + (size_t)b * TV_;
    _Float16* Y1 = Hb + (size_t)(1 + 2 * s) * ASZ + (size_t)b * TV_;
    _Float16* Y2 = Hb + (size_t)(2 + 2 * s) * ASZ + (size_t)b * TV_;

    const _Float16* ax = At + (size_t)(wbase + row16) * V_ + kg * 8;  // A: At w-rows
    const _Float16* bx = Xb + (size_t)row16 * V_ + kg * 8;            // B: X t-rows

    f32x4 acc[4][4];
#pragma unroll
    for (int i = 0; i < 4; ++i)
#pragma unroll
        for (int j = 0; j < 4; ++j) acc[i][j] = (f32x4){0.f, 0.f, 0.f, 0.f};

    for (int v0 = 0; v0 < V_; v0 += 32) {
        f16x8 a[4], bf[4];
#pragma unroll
        for (int mt = 0; mt < 4; ++mt)
            a[mt] = *(const f16x8*)(ax + (size_t)mt * 16 * V_ + v0);
#pragma unroll
        for (int nt = 0; nt < 4; ++nt)
            bf[nt] = *(const f16x8*)(bx + (size_t)nt * 16 * V_ + v0);
#pragma unroll
        for (int nt = 0; nt < 4; ++nt)
#pragma unroll
            for (int mt = 0; mt < 4; ++mt)
                acc[mt][nt] = __builtin_amdgcn_mfma_f32_16x16x32_f16(a[mt], bf[nt], acc[mt][nt], 0, 0, 0);
    }

    // acc -> swizzled LDS (8B vector writes)
#pragma unroll
    for (int mt = 0; mt < 4; ++mt)
#pragma unroll
        for (int nt = 0; nt < 4; ++nt) {
            int t = nt * 16 + row16;
            int w = wbase + mt * 16 + kg * 4;
            f16x4 h;
            h[0] = (_Float16)acc[mt][nt][0];
            h[1] = (_Float16)acc[mt][nt][1];
            h[2] = (_Float16)acc[mt][nt][2];
            h[3] = (_Float16)acc[mt][nt][3];
            int byte = (t * V_ + w) * 2;
            *(f16x4*)((char*)x1s + (byte ^ ((t & 7) << 4))) = h;
        }
    __syncthreads();

    // Y1 copy: LDS -> global, 16B per lane, fully coalesced
#pragma unroll
    for (int k = 0; k < 8; ++k) {
        int lin = k * 512 + tid;
        int t = lin >> 6;
        int v8 = (lin & 63) << 3;
        int byte = (t * V_ + v8) * 2;
        f16x8 val = *(const f16x8*)((const char*)x1s + (byte ^ ((t & 7) << 4)));
        *(f16x8*)&Y1[(size_t)t * V_ + v8] = val;
    }

    // hop 2: B from swizzled LDS
#pragma unroll
    for (int i = 0; i < 4; ++i)
#pragma unroll
        for (int j = 0; j < 4; ++j) acc[i][j] = (f32x4){0.f, 0.f, 0.f, 0.f};

    for (int v0 = 0; v0 < V_; v0 += 32) {
        f16x8 a[4], bf[4];
#pragma unroll
        for (int mt = 0; mt < 4; ++mt)
            a[mt] = *(const f16x8*)(ax + (size_t)mt * 16 * V_ + v0);
#pragma unroll
        for (int nt = 0; nt < 4; ++nt) {
            int t = nt * 16 + row16;
            int byte = (t * V_ + v0 + kg * 8) * 2;
            bf[nt] = *(const f16x8*)((const char*)x1s + (byte ^ ((t & 7) << 4)));
        }
#pragma unroll
        for (int nt = 0; nt < 4; ++nt)
#pragma unroll
            for (int mt = 0; mt < 4; ++mt)
                acc[mt][nt] = __builtin_amdgcn_mfma_f32_16x16x32_f16(a[mt], bf[nt], acc[mt][nt], 0, 0, 0);
    }
    __syncthreads();   // all x1s reads complete before overwrite

#pragma unroll
    for (int mt = 0; mt < 4; ++mt)
#pragma unroll
        for (int nt = 0; nt < 4; ++nt) {
            int t = nt * 16 + row16;
            int w = wbase + mt * 16 + kg * 4;
            f16x4 h;
            h[0] = (_Float16)acc[mt][nt][0];
            h[1] = (_Float16)acc[mt][nt][1];
            h[2] = (_Float16)acc[mt][nt][2];
            h[3] = (_Float16)acc[mt][nt][3];
            int byte = (t * V_ + w) * 2;
            *(f16x4*)((char*)x1s + (byte ^ ((t & 7) << 4))) = h;
        }
    __syncthreads();

#pragma unroll
    for (int k = 0; k < 8; ++k) {
        int lin = k * 512 + tid;
        int t = lin >> 6;
        int v8 = (lin & 63) << 3;
        int byte = (t * V_ + v8) * 2;
        f16x8 val = *(const f16x8*)((const char*)x1s + (byte ^ ((t & 7) << 4)));
        *(f16x8*)&Y2[(size_t)t * V_ + v8] = val;
    }
}

// ---------------------------------------------------------------------------
// Kernel 6: MFMA epilogue GEMM, 64o x 32v x 8t per block (full-sector reads).
// out[ng,o,v,t] = PReLU( bias[o] + sum_{k=0..255} Wcat[o,k] * H_k[nl][t][v] )
// ---------------------------------------------------------------------------
__global__ __launch_bounds__(256) void epi_kernel(
    const _Float16* __restrict__ H, unsigned long long ASZ,
    const _Float16* __restrict__ Wcat, const float* __restrict__ bias,
    const float* __restrict__ alpha_p, float* __restrict__ out, int n0)
{
    const int v0 = blockIdx.x * 32;
    const int t0 = blockIdx.y * 8;
    const int nl = blockIdx.z;
    const int ng = n0 + nl;
    const int tid = threadIdx.x;
    const int lane = tid & 63;
    const int wv = tid >> 6;      // wave 0..3 -> t pair
    const int row16 = lane & 15;
    const int kg = lane >> 4;

    f32x4 acc[2][2][4];           // [j: t][vs: v-half][mt: o-tile]
#pragma unroll
    for (int j = 0; j < 2; ++j)
#pragma unroll
        for (int vs = 0; vs < 2; ++vs)
#pragma unroll
            for (int mt = 0; mt < 4; ++mt) acc[j][vs][mt] = (f32x4){0.f, 0.f, 0.f, 0.f};

    const size_t pb = ((size_t)(nl * C_ + kg * 8)) * TV_
                    + (size_t)(t0 + wv * 2) * V_ + v0 + row16;

#pragma unroll
    for (int ks = 0; ks < 8; ++ks) {
        const _Float16* Hk = H + (size_t)ks * ASZ;
        f16x8 a[4];
#pragma unroll
        for (int mt = 0; mt < 4; ++mt)
            a[mt] = *(const f16x8*)(Wcat + (mt * 16 + row16) * 256 + ks * 32 + kg * 8);
#pragma unroll
        for (int j = 0; j < 2; ++j)
#pragma unroll
            for (int vs = 0; vs < 2; ++vs) {
                const _Float16* hp = Hk + pb + (size_t)j * V_ + vs * 16;
                f16x8 bf;
#pragma unroll
                for (int e = 0; e < 8; ++e) bf[e] = hp[(size_t)e * TV_];
#pragma unroll
                for (int mt = 0; mt < 4; ++mt)
                    acc[j][vs][mt] = __builtin_amdgcn_mfma_f32_16x16x32_f16(a[mt], bf, acc[j][vs][mt], 0, 0, 0);
            }
    }

    // C transpose via LDS: sC[o16][v33-pad][t9-pad]
    __shared__ float sC[16 * 33 * 9];
    const float al = alpha_p[0];
    const int ot = tid >> 4;
    const int vvt = tid & 15;

    for (int mt = 0; mt < 4; ++mt) {
#pragma unroll
        for (int j = 0; j < 2; ++j)
#pragma unroll
            for (int vs = 0; vs < 2; ++vs)
#pragma unroll
                for (int r = 0; r < 4; ++r)
                    sC[((kg * 4 + r) * 33 + vs * 16 + row16) * 9 + wv * 2 + j] = acc[j][vs][mt][r];
        __syncthreads();
        const float bo = bias[mt * 16 + ot];
#pragma unroll
        for (int vh = 0; vh < 2; ++vh) {
            const int vl = vvt + vh * 16;
            float vals[8];
#pragma unroll
            for (int tt = 0; tt < 8; ++tt) {
                float u = sC[(ot * 33 + vl) * 9 + tt] + bo;
                vals[tt] = u > 0.f ? u : al * u;
            }
            float* op = out + (((size_t)ng * OC_ + mt * 16 + ot) * V_ + v0 + vl) * T_ + t0;
            *(float4*)&op[0] = make_float4(vals[0], vals[1], vals[2], vals[3]);
            *(float4*)&op[4] = make_float4(vals[4], vals[5], vals[6], vals[7]);
        }
        __syncthreads();
    }
}

// ---------------------------------------------------------------------------
extern "C" void kernel_launch(void* const* d_in, const int* in_sizes, int n_in,
                              void* d_out, int out_size, void* d_ws, size_t ws_size,
                              hipStream_t stream)
{
    const float* x       = (const float*)d_in[0];
    const float* t_in    = (const float*)d_in[1];
    const float* A0      = (const float*)d_in[2];
    const float* A1      = (const float*)d_in[3];
    const float* A2      = (const float*)d_in[4];
    const float* factors = (const float*)d_in[5];
    const float* Wq      = (const float*)d_in[6];
    const float* Wk      = (const float*)d_in[7];
    const float* W_out   = (const float*)d_in[8];
    const float* b_out   = (const float*)d_in[9];
    const float* W_res   = (const float*)d_in[10];
    const float* b_res   = (const float*)d_in[11];
    const float* gamma   = (const float*)d_in[12];
    const float* beta    = (const float*)d_in[13];
    const float* mean    = (const float*)d_in[14];
    const float* var     = (const float*)d_in[15];
    const float* alpha   = (const float*)d_in[16];
    float* out = (float*)d_out;

    float* att = (float*)d_ws;                               // 262144 f32
    float* S    = att + (size_t)N_ * H_ * T_ * T_;           // 65536 f32
    float* bias = S + (size_t)N_ * T_ * T_;                  // 64 f32
    _Float16* At16 = (_Float16*)(bias + 64);                 // 3*V*V f16
    _Float16* Wcat = At16 + (size_t)3 * V_ * V_;             // 64*256 f16
    _Float16* Hbase = Wcat + (size_t)64 * 256;               // 8 chunk arrays

    const size_t fixed = ((size_t)N_ * H_ * T_ * T_ + (size_t)N_ * T_ * T_ + 64) * 4
                       + ((size_t)3 * V_ * V_ + 64 * 256) * 2;
    int Nc = 16;
    while (Nc > 1 && fixed + (size_t)8 * Nc * C_ * T_ * V_ * 2 > ws_size) Nc >>= 1;
    const size_t ASZ = (size_t)Nc * C_ * T_ * V_;   // elements per chunk array

    att_kernel<<<N_ * H_, 64, 0, stream>>>(t_in, factors, Wq, Wk, att);
    sred_kernel<<<(N_ * T_ * T_ + 255) / 256, 256, 0, stream>>>(att, S);
    prepAt_kernel<<<dim3(16, 16, 3), 256, 0, stream>>>(A0, A1, A2, At16);
    prepW_kernel<<<1, 256, 0, stream>>>(W_out, b_out, W_res, b_res,
                                        gamma, beta, mean, var, Wcat, bias);

    for (int n0 = 0; n0 < N_; n0 += Nc) {
        const int nsl = Nc * C_;
        xtT_kernel<<<dim3(2, nsl), 256, 0, stream>>>(x, S, Hbase, n0);
        prepxT_kernel<<<dim3(16, 2, nsl), 256, 0, stream>>>(x, Hbase + (size_t)7 * ASZ, n0);
        hopf_kernel<<<dim3(nsl, 3), 512, 0, stream>>>(At16, Hbase, (unsigned long long)ASZ);
        epi_kernel<<<dim3(16, 8, Nc), 256, 0, stream>>>(
            Hbase, (unsigned long long)ASZ, Wcat, bias, alpha, out, n0);
    }
}

// Round 6
// 544.484 us; speedup vs baseline: 3.1495x; 1.0236x over previous
//
#include <hip/hip_runtime.h>

namespace {
constexpr int N_ = 16, C_ = 32, V_ = 512, T_ = 64;
constexpr int H_ = 4, D_ = 16, OC_ = 64;
constexpr int EMB_ = 64;
constexpr int GCIN_ = 7 * C_;         // 224
constexpr int TV_ = T_ * V_;          // 32768 (one slice, [t][v] f16 layout)
}

typedef _Float16 f16x8 __attribute__((ext_vector_type(8)));
typedef _Float16 f16x4 __attribute__((ext_vector_type(4)));
typedef float f32x4 __attribute__((ext_vector_type(4)));

// ---------------------------------------------------------------------------
// Kernel 1: per-(n,h) attention rows. att[n,h,t,p] = softmax_p(q_t . k_p / 4)
// ---------------------------------------------------------------------------
__global__ __launch_bounds__(64) void att_kernel(
    const float* __restrict__ t_in, const float* __restrict__ factors,
    const float* __restrict__ Wq, const float* __restrict__ Wk,
    float* __restrict__ att)
{
    const int n = blockIdx.x >> 2;
    const int h = blockIdx.x & 3;
    const int t = threadIdx.x;   // 0..63

    __shared__ float wq_l[EMB_][D_];
    __shared__ float wk_l[EMB_][D_];
    __shared__ float k_l[T_][D_ + 1];

#pragma unroll
    for (int d = 0; d < D_; ++d) {
        wq_l[t][d] = Wq[(h * EMB_ + t) * D_ + d];
        wk_l[t][d] = Wk[(h * EMB_ + t) * D_ + d];
    }
    __syncthreads();

    const float tv = t_in[n * T_ + t];
    const float fh = factors[h];
    float emb[EMB_];
#pragma unroll
    for (int j = 0; j < 32; ++j) {
        float dt = __expf((float)(2 * j) * fh);
        float ph = tv * dt;
        float s, c;
        __sincosf(ph, &s, &c);
        emb[j] = s;
        emb[j + 32] = c;
    }

    float q[D_];
#pragma unroll
    for (int d = 0; d < D_; ++d) {
        float aq = 0.f, ak = 0.f;
#pragma unroll
        for (int f = 0; f < EMB_; ++f) {
            aq += emb[f] * wq_l[f][d];
            ak += emb[f] * wk_l[f][d];
        }
        q[d] = aq;
        k_l[t][d] = ak;
    }
    __syncthreads();

    float L[T_];
    float m = -1e30f;
#pragma unroll
    for (int j = 0; j < T_; ++j) {
        float a = 0.f;
#pragma unroll
        for (int d = 0; d < D_; ++d) a += q[d] * k_l[j][d];
        a *= 0.25f;
        L[j] = a;
        m = fmaxf(m, a);
    }
    float ssum = 0.f;
#pragma unroll
    for (int j = 0; j < T_; ++j) {
        float e = __expf(L[j] - m);
        L[j] = e;
        ssum += e;
    }
    const float inv = 1.f / ssum;
    float* arow = att + (((size_t)(n * H_ + h) * T_ + t) * T_);
#pragma unroll
    for (int j = 0; j < T_; ++j) arow[j] = L[j] * inv;
}

// ---------------------------------------------------------------------------
// Kernel 2: S[n,i,j] = sum_h att[n,h,i,j]
// ---------------------------------------------------------------------------
__global__ __launch_bounds__(256) void sred_kernel(
    const float* __restrict__ att, float* __restrict__ S)
{
    int g = blockIdx.x * 256 + threadIdx.x;
    if (g >= N_ * T_ * T_) return;
    int n = g / (T_ * T_);
    int ij = g - n * (T_ * T_);
    float a = 0.f;
#pragma unroll
    for (int h = 0; h < H_; ++h) a += att[(size_t)(n * H_ + h) * (T_ * T_) + ij];
    S[g] = a;
}

// ---------------------------------------------------------------------------
// Kernel 3: At16[s][w][v] = (f16) A_s[v][w]   (transpose + cast)
// ---------------------------------------------------------------------------
__global__ __launch_bounds__(256) void prepAt_kernel(
    const float* __restrict__ A0, const float* __restrict__ A1,
    const float* __restrict__ A2, _Float16* __restrict__ At16)
{
    const int s = blockIdx.z;
    const float* A = (s == 0) ? A0 : ((s == 1) ? A1 : A2);
    const int v0 = blockIdx.y * 32, w0 = blockIdx.x * 32;
    const int tid = threadIdx.x;
    __shared__ float sT[32][33];
#pragma unroll
    for (int k = 0; k < 4; ++k) {
        int lin = k * 256 + tid;
        int i = lin >> 5, w = lin & 31;
        sT[i][w] = A[(size_t)(v0 + i) * V_ + w0 + w];
    }
    __syncthreads();
#pragma unroll
    for (int k = 0; k < 4; ++k) {
        int lin = k * 256 + tid;
        int j = lin >> 5, i = lin & 31;
        At16[(size_t)s * V_ * V_ + (size_t)(w0 + j) * V_ + v0 + i] = (_Float16)sT[i][j];
    }
}

// ---------------------------------------------------------------------------
// Kernel 3b: xT16[b][t][v] = (f16) x[n0*C + b][v][t]  (residual channels)
// ---------------------------------------------------------------------------
__global__ __launch_bounds__(256) void prepxT_kernel(
    const float* __restrict__ x, _Float16* __restrict__ xT, int n0)
{
    const int b = blockIdx.z;
    const int v0 = blockIdx.x * 32;
    const int t0 = blockIdx.y * 32;
    const int tid = threadIdx.x;
    __shared__ float sT[32][33];
    const float* xb = x + ((size_t)(n0 * C_) + b) * (size_t)(V_ * T_);
    {
        int vi = tid >> 3, tq = tid & 7;
        *(float4*)&sT[vi][tq * 4] = *(const float4*)&xb[(size_t)(v0 + vi) * T_ + t0 + tq * 4];
    }
    __syncthreads();
    {
        int tj = tid >> 3, vq = tid & 7;
        f16x4 o4;
        o4[0] = (_Float16)sT[vq * 4 + 0][tj];
        o4[1] = (_Float16)sT[vq * 4 + 1][tj];
        o4[2] = (_Float16)sT[vq * 4 + 2][tj];
        o4[3] = (_Float16)sT[vq * 4 + 3][tj];
        *(f16x4*)&xT[(size_t)b * TV_ + (size_t)(t0 + tj) * V_ + v0 + vq * 4] = o4;
    }
}

// ---------------------------------------------------------------------------
// Kernel 3c: Wcat[o][k] f16 (k<224: W_out; k>=224: BN-scaled W_res), bias[o].
// ---------------------------------------------------------------------------
__global__ __launch_bounds__(256) void prepW_kernel(
    const float* __restrict__ W_out, const float* __restrict__ b_out,
    const float* __restrict__ W_res, const float* __restrict__ b_res,
    const float* __restrict__ gamma, const float* __restrict__ beta,
    const float* __restrict__ mean, const float* __restrict__ var,
    _Float16* __restrict__ Wcat, float* __restrict__ bias)
{
    const int tid = threadIdx.x;
    const int o = tid & 63;
    const int kb = tid >> 6;   // 0..3
    const float rs = gamma[o] * rsqrtf(var[o] + 1e-5f);
    for (int kk = 0; kk < 64; ++kk) {
        int k = kb * 64 + kk;
        float w = (k < GCIN_) ? W_out[o * GCIN_ + k] : rs * W_res[o * C_ + (k - GCIN_)];
        Wcat[o * 256 + k] = (_Float16)w;
    }
    if (tid < 64) bias[tid] = b_out[tid] + beta[tid] + rs * (b_res[tid] - mean[tid]);
}

// ---------------------------------------------------------------------------
// Kernel 4: xtT[b][p][v] = sum_j S[n][p][j] * x[b][v][j]   (f16 out, MFMA)
// Swapped roles: A = x v-rows (m=v), B = S rows (n=p). D[v][p]: lane holds
// 4 consecutive v at fixed p -> 8B vector stores into XT[p][v].
// ---------------------------------------------------------------------------
__global__ __launch_bounds__(256) void xtT_kernel(
    const float* __restrict__ x, const float* __restrict__ S,
    _Float16* __restrict__ XT, int n0)
{
    const int b = blockIdx.y;
    const int n = n0 + b / C_;
    const int lane = threadIdx.x & 63;
    const int wav = threadIdx.x >> 6;
    const int vbase = blockIdx.x * 256 + wav * 64;
    const int row16 = lane & 15;
    const int kg = lane >> 4;

    const float* Sn = S + (size_t)n * (T_ * T_);
    const float* xb = x + ((size_t)(n0 * C_) + b) * (V_ * T_);

    f32x4 acc[4][4];
#pragma unroll
    for (int i = 0; i < 4; ++i)
#pragma unroll
        for (int j = 0; j < 4; ++j) acc[i][j] = (f32x4){0.f, 0.f, 0.f, 0.f};

#pragma unroll
    for (int ks = 0; ks < 2; ++ks) {
        f16x8 a[4], bf[4];
#pragma unroll
        for (int mt = 0; mt < 4; ++mt) {   // A = x rows (m = v)
            const float* p = xb + (size_t)(vbase + mt * 16 + row16) * T_ + ks * 32 + kg * 8;
            float4 u = *(const float4*)p;
            float4 w = *(const float4*)(p + 4);
            f16x8 t8;
            t8[0] = (_Float16)u.x; t8[1] = (_Float16)u.y; t8[2] = (_Float16)u.z; t8[3] = (_Float16)u.w;
            t8[4] = (_Float16)w.x; t8[5] = (_Float16)w.y; t8[6] = (_Float16)w.z; t8[7] = (_Float16)w.w;
            a[mt] = t8;
        }
#pragma unroll
        for (int nt = 0; nt < 4; ++nt) {   // B = S rows (n = p)
            const float* p = Sn + (size_t)(nt * 16 + row16) * T_ + ks * 32 + kg * 8;
            float4 u = *(const float4*)p;
            float4 w = *(const float4*)(p + 4);
            f16x8 t8;
            t8[0] = (_Float16)u.x; t8[1] = (_Float16)u.y; t8[2] = (_Float16)u.z; t8[3] = (_Float16)u.w;
            t8[4] = (_Float16)w.x; t8[5] = (_Float16)w.y; t8[6] = (_Float16)w.z; t8[7] = (_Float16)w.w;
            bf[nt] = t8;
        }
#pragma unroll
        for (int nt = 0; nt < 4; ++nt)
#pragma unroll
            for (int mt = 0; mt < 4; ++mt)
                acc[mt][nt] = __builtin_amdgcn_mfma_f32_16x16x32_f16(a[mt], bf[nt], acc[mt][nt], 0, 0, 0);
    }

    _Float16* Yb = XT + (size_t)b * TV_;
#pragma unroll
    for (int mt = 0; mt < 4; ++mt)
#pragma unroll
        for (int nt = 0; nt < 4; ++nt) {
            int p = nt * 16 + row16;
            int v = vbase + mt * 16 + kg * 4;
            f16x4 h;
            h[0] = (_Float16)acc[mt][nt][0];
            h[1] = (_Float16)acc[mt][nt][1];
            h[2] = (_Float16)acc[mt][nt][2];
            h[3] = (_Float16)acc[mt][nt][3];
            *(f16x4*)&Yb[(size_t)p * V_ + v] = h;
        }
}

// ---------------------------------------------------------------------------
// Kernel 5: fused double diffusion hop, 2-deep register-pipelined K-loop.
// A = At w-rows (m=w), B = X t-rows (n=t). D[w][t]: lane holds 4 consecutive
// w at fixed t -> 8B LDS stores; global Y1/Y2 via LDS as 16B coalesced.
// LDS swizzle: byte ^= (t&7)<<4.
// ---------------------------------------------------------------------------
__global__ __launch_bounds__(512) void hopf_kernel(
    const _Float16* __restrict__ At16, _Float16* __restrict__ Hb,
    unsigned long long ASZ)
{
    const int b = blockIdx.x;   // slice (n,c)
    const int s = blockIdx.y;   // support
    const int tid = threadIdx.x;
    const int lane = tid & 63;
    const int wav = tid >> 6;
    const int wbase = wav * 64;
    const int row16 = lane & 15;
    const int kg = lane >> 4;

    __shared__ _Float16 x1s[T_ * V_];   // 64 KiB

    const _Float16* At = At16 + (size_t)s * V_ * V_;
    const _Float16* Xb = Hb + (size_t)b * TV_;
    _Float16* Y1 = Hb + (size_t)(1 + 2 * s) * ASZ + (size_t)b * TV_;
    _Float16* Y2 = Hb + (size_t)(2 + 2 * s) * ASZ + (size_t)b * TV_;

    const _Float16* ax = At + (size_t)(wbase + row16) * V_ + kg * 8;  // A: At w-rows
    const _Float16* bx = Xb + (size_t)row16 * V_ + kg * 8;            // B: X t-rows

    f32x4 acc[4][4];
    f16x8 aC[4], bC[4], aN[4], bN[4];

    // ---- hop 1 (B from global) ----
#pragma unroll
    for (int i = 0; i < 4; ++i)
#pragma unroll
        for (int j = 0; j < 4; ++j) acc[i][j] = (f32x4){0.f, 0.f, 0.f, 0.f};

#pragma unroll
    for (int i = 0; i < 4; ++i) {
        aC[i] = *(const f16x8*)(ax + (size_t)i * 16 * V_);
        bC[i] = *(const f16x8*)(bx + (size_t)i * 16 * V_);
    }
#pragma unroll
    for (int v0 = 0; v0 < V_; v0 += 32) {
        if (v0 + 32 < V_) {
#pragma unroll
            for (int i = 0; i < 4; ++i) {
                aN[i] = *(const f16x8*)(ax + (size_t)i * 16 * V_ + v0 + 32);
                bN[i] = *(const f16x8*)(bx + (size_t)i * 16 * V_ + v0 + 32);
            }
        }
#pragma unroll
        for (int nt = 0; nt < 4; ++nt)
#pragma unroll
            for (int mt = 0; mt < 4; ++mt)
                acc[mt][nt] = __builtin_amdgcn_mfma_f32_16x16x32_f16(aC[mt], bC[nt], acc[mt][nt], 0, 0, 0);
#pragma unroll
        for (int i = 0; i < 4; ++i) { aC[i] = aN[i]; bC[i] = bN[i]; }
    }

    // acc -> swizzled LDS (8B vector writes)
#pragma unroll
    for (int mt = 0; mt < 4; ++mt)
#pragma unroll
        for (int nt = 0; nt < 4; ++nt) {
            int t = nt * 16 + row16;
            int w = wbase + mt * 16 + kg * 4;
            f16x4 h;
            h[0] = (_Float16)acc[mt][nt][0];
            h[1] = (_Float16)acc[mt][nt][1];
            h[2] = (_Float16)acc[mt][nt][2];
            h[3] = (_Float16)acc[mt][nt][3];
            int byte = (t * V_ + w) * 2;
            *(f16x4*)((char*)x1s + (byte ^ ((t & 7) << 4))) = h;
        }
    __syncthreads();

    // Y1 copy: LDS -> global, 16B per lane, fully coalesced
#pragma unroll
    for (int k = 0; k < 8; ++k) {
        int lin = k * 512 + tid;
        int t = lin >> 6;
        int v8 = (lin & 63) << 3;
        int byte = (t * V_ + v8) * 2;
        f16x8 val = *(const f16x8*)((const char*)x1s + (byte ^ ((t & 7) << 4)));
        *(f16x8*)&Y1[(size_t)t * V_ + v8] = val;
    }

    // ---- hop 2 (B from swizzled LDS), same 2-deep pipeline ----
#pragma unroll
    for (int i = 0; i < 4; ++i)
#pragma unroll
        for (int j = 0; j < 4; ++j) acc[i][j] = (f32x4){0.f, 0.f, 0.f, 0.f};

#pragma unroll
    for (int i = 0; i < 4; ++i) {
        aC[i] = *(const f16x8*)(ax + (size_t)i * 16 * V_);
        int t = i * 16 + row16;
        int byte = (t * V_ + kg * 8) * 2;
        bC[i] = *(const f16x8*)((const char*)x1s + (byte ^ ((t & 7) << 4)));
    }
#pragma unroll
    for (int v0 = 0; v0 < V_; v0 += 32) {
        if (v0 + 32 < V_) {
#pragma unroll
            for (int i = 0; i < 4; ++i) {
                aN[i] = *(const f16x8*)(ax + (size_t)i * 16 * V_ + v0 + 32);
                int t = i * 16 + row16;
                int byte = (t * V_ + v0 + 32 + kg * 8) * 2;
                bN[i] = *(const f16x8*)((const char*)x1s + (byte ^ ((t & 7) << 4)));
            }
        }
#pragma unroll
        for (int nt = 0; nt < 4; ++nt)
#pragma unroll
            for (int mt = 0; mt < 4; ++mt)
                acc[mt][nt] = __builtin_amdgcn_mfma_f32_16x16x32_f16(aC[mt], bC[nt], acc[mt][nt], 0, 0, 0);
#pragma unroll
        for (int i = 0; i < 4; ++i) { aC[i] = aN[i]; bC[i] = bN[i]; }
    }
    __syncthreads();   // all x1s reads complete before overwrite

#pragma unroll
    for (int mt = 0; mt < 4; ++mt)
#pragma unroll
        for (int nt = 0; nt < 4; ++nt) {
            int t = nt * 16 + row16;
            int w = wbase + mt * 16 + kg * 4;
            f16x4 h;
            h[0] = (_Float16)acc[mt][nt][0];
            h[1] = (_Float16)acc[mt][nt][1];
            h[2] = (_Float16)acc[mt][nt][2];
            h[3] = (_Float16)acc[mt][nt][3];
            int byte = (t * V_ + w) * 2;
            *(f16x4*)((char*)x1s + (byte ^ ((t & 7) << 4))) = h;
        }
    __syncthreads();

#pragma unroll
    for (int k = 0; k < 8; ++k) {
        int lin = k * 512 + tid;
        int t = lin >> 6;
        int v8 = (lin & 63) << 3;
        int byte = (t * V_ + v8) * 2;
        f16x8 val = *(const f16x8*)((const char*)x1s + (byte ^ ((t & 7) << 4)));
        *(f16x8*)&Y2[(size_t)t * V_ + v8] = val;
    }
}

// ---------------------------------------------------------------------------
// Kernel 6: MFMA epilogue GEMM, 64o x 32v x 8t per block (full-sector reads).
// out[ng,o,v,t] = PReLU( bias[o] + sum_{k=0..255} Wcat[o,k] * H_k[nl][t][v] )
// ---------------------------------------------------------------------------
__global__ __launch_bounds__(256) void epi_kernel(
    const _Float16* __restrict__ H, unsigned long long ASZ,
    const _Float16* __restrict__ Wcat, const float* __restrict__ bias,
    const float* __restrict__ alpha_p, float* __restrict__ out, int n0)
{
    const int v0 = blockIdx.x * 32;
    const int t0 = blockIdx.y * 8;
    const int nl = blockIdx.z;
    const int ng = n0 + nl;
    const int tid = threadIdx.x;
    const int lane = tid & 63;
    const int wv = tid >> 6;      // wave 0..3 -> t pair
    const int row16 = lane & 15;
    const int kg = lane >> 4;

    f32x4 acc[2][2][4];           // [j: t][vs: v-half][mt: o-tile]
#pragma unroll
    for (int j = 0; j < 2; ++j)
#pragma unroll
        for (int vs = 0; vs < 2; ++vs)
#pragma unroll
            for (int mt = 0; mt < 4; ++mt) acc[j][vs][mt] = (f32x4){0.f, 0.f, 0.f, 0.f};

    const size_t pb = ((size_t)(nl * C_ + kg * 8)) * TV_
                    + (size_t)(t0 + wv * 2) * V_ + v0 + row16;

#pragma unroll
    for (int ks = 0; ks < 8; ++ks) {
        const _Float16* Hk = H + (size_t)ks * ASZ;
        f16x8 a[4];
#pragma unroll
        for (int mt = 0; mt < 4; ++mt)
            a[mt] = *(const f16x8*)(Wcat + (mt * 16 + row16) * 256 + ks * 32 + kg * 8);
#pragma unroll
        for (int j = 0; j < 2; ++j)
#pragma unroll
            for (int vs = 0; vs < 2; ++vs) {
                const _Float16* hp = Hk + pb + (size_t)j * V_ + vs * 16;
                f16x8 bf;
#pragma unroll
                for (int e = 0; e < 8; ++e) bf[e] = hp[(size_t)e * TV_];
#pragma unroll
                for (int mt = 0; mt < 4; ++mt)
                    acc[j][vs][mt] = __builtin_amdgcn_mfma_f32_16x16x32_f16(a[mt], bf, acc[j][vs][mt], 0, 0, 0);
            }
    }

    // C transpose via LDS: sC[o16][v33-pad][t9-pad]
    __shared__ float sC[16 * 33 * 9];
    const float al = alpha_p[0];
    const int ot = tid >> 4;
    const int vvt = tid & 15;

    for (int mt = 0; mt < 4; ++mt) {
#pragma unroll
        for (int j = 0; j < 2; ++j)
#pragma unroll
            for (int vs = 0; vs < 2; ++vs)
#pragma unroll
                for (int r = 0; r < 4; ++r)
                    sC[((kg * 4 + r) * 33 + vs * 16 + row16) * 9 + wv * 2 + j] = acc[j][vs][mt][r];
        __syncthreads();
        const float bo = bias[mt * 16 + ot];
#pragma unroll
        for (int vh = 0; vh < 2; ++vh) {
            const int vl = vvt + vh * 16;
            float vals[8];
#pragma unroll
            for (int tt = 0; tt < 8; ++tt) {
                float u = sC[(ot * 33 + vl) * 9 + tt] + bo;
                vals[tt] = u > 0.f ? u : al * u;
            }
            float* op = out + (((size_t)ng * OC_ + mt * 16 + ot) * V_ + v0 + vl) * T_ + t0;
            *(float4*)&op[0] = make_float4(vals[0], vals[1], vals[2], vals[3]);
            *(float4*)&op[4] = make_float4(vals[4], vals[5], vals[6], vals[7]);
        }
        __syncthreads();
    }
}

// ---------------------------------------------------------------------------
extern "C" void kernel_launch(void* const* d_in, const int* in_sizes, int n_in,
                              void* d_out, int out_size, void* d_ws, size_t ws_size,
                              hipStream_t stream)
{
    const float* x       = (const float*)d_in[0];
    const float* t_in    = (const float*)d_in[1];
    const float* A0      = (const float*)d_in[2];
    const float* A1      = (const float*)d_in[3];
    const float* A2      = (const float*)d_in[4];
    const float* factors = (const float*)d_in[5];
    const float* Wq      = (const float*)d_in[6];
    const float* Wk      = (const float*)d_in[7];
    const float* W_out   = (const float*)d_in[8];
    const float* b_out   = (const float*)d_in[9];
    const float* W_res   = (const float*)d_in[10];
    const float* b_res   = (const float*)d_in[11];
    const float* gamma   = (const float*)d_in[12];
    const float* beta    = (const float*)d_in[13];
    const float* mean    = (const float*)d_in[14];
    const float* var     = (const float*)d_in[15];
    const float* alpha   = (const float*)d_in[16];
    float* out = (float*)d_out;

    float* att = (float*)d_ws;                               // 262144 f32
    float* S    = att + (size_t)N_ * H_ * T_ * T_;           // 65536 f32
    float* bias = S + (size_t)N_ * T_ * T_;                  // 64 f32
    _Float16* At16 = (_Float16*)(bias + 64);                 // 3*V*V f16
    _Float16* Wcat = At16 + (size_t)3 * V_ * V_;             // 64*256 f16
    _Float16* Hbase = Wcat + (size_t)64 * 256;               // 8 chunk arrays

    const size_t fixed = ((size_t)N_ * H_ * T_ * T_ + (size_t)N_ * T_ * T_ + 64) * 4
                       + ((size_t)3 * V_ * V_ + 64 * 256) * 2;
    int Nc = 16;
    while (Nc > 1 && fixed + (size_t)8 * Nc * C_ * T_ * V_ * 2 > ws_size) Nc >>= 1;
    const size_t ASZ = (size_t)Nc * C_ * T_ * V_;   // elements per chunk array

    att_kernel<<<N_ * H_, 64, 0, stream>>>(t_in, factors, Wq, Wk, att);
    sred_kernel<<<(N_ * T_ * T_ + 255) / 256, 256, 0, stream>>>(att, S);
    prepAt_kernel<<<dim3(16, 16, 3), 256, 0, stream>>>(A0, A1, A2, At16);
    prepW_kernel<<<1, 256, 0, stream>>>(W_out, b_out, W_res, b_res,
                                        gamma, beta, mean, var, Wcat, bias);

    for (int n0 = 0; n0 < N_; n0 += Nc) {
        const int nsl = Nc * C_;
        xtT_kernel<<<dim3(2, nsl), 256, 0, stream>>>(x, S, Hbase, n0);
        prepxT_kernel<<<dim3(16, 2, nsl), 256, 0, stream>>>(x, Hbase + (size_t)7 * ASZ, n0);
        hopf_kernel<<<dim3(nsl, 3), 512, 0, stream>>>(At16, Hbase, (unsigned long long)ASZ);
        epi_kernel<<<dim3(16, 8, Nc), 256, 0, stream>>>(
            Hbase, (unsigned long long)ASZ, Wcat, bias, alpha, out, n0);
    }
}